// Round 16
// baseline (110.521 us; speedup 1.0000x reference)
//
#include <hip/hip_runtime.h>

// Problem constants
#define BATCH 1024
#define RR    49        // 7*7 spatial
#define SP    12544     // 256*49 per-batch patch elems; also FLAT
#define KVALID 625      // nonzero correlation outputs per batch
#define KPAD   640      // padded K for GEMM1
#define REP_N  1024

typedef __attribute__((ext_vector_type(4))) float f32x4;
typedef __attribute__((ext_vector_type(8))) short s16x8;   // 8 bf16 (4 VGPRs)

// ---- bf16 split helpers (RNE) ----
__device__ __forceinline__ unsigned short f2bf_rne(float f) {
    unsigned int u = __float_as_uint(f);
    unsigned int r = u + 0x7FFFu + ((u >> 16) & 1u);
    return (unsigned short)(r >> 16);
}
__device__ __forceinline__ float bf2f(unsigned short h) {
    return __uint_as_float(((unsigned int)h) << 16);
}
__device__ __forceinline__ void split2(float v, unsigned short& h, unsigned short& l) {
    h = f2bf_rne(v);
    l = f2bf_rne(v - bf2f(h));
}
// Pack two floats to bf16 pair (verified numerically R4-R15).
__device__ __forceinline__ unsigned int cvtpk_bf16(float a, float b) {
    unsigned int r;
    asm("v_cvt_pk_bf16_f32 %0, %1, %2" : "=v"(r) : "v"(a), "v"(b));
    return r;
}
// Split 8 floats -> hi/lo s16x8 fragments.
__device__ __forceinline__ void cvt8(const float* v, s16x8& hv, s16x8& lv) {
    unsigned int* hp = (unsigned int*)&hv;
    unsigned int* lp = (unsigned int*)&lv;
    #pragma unroll
    for (int i = 0; i < 4; ++i) {
        float v0 = v[2 * i], v1 = v[2 * i + 1];
        unsigned int ph = cvtpk_bf16(v0, v1);
        float h0 = __uint_as_float(ph << 16);
        float h1 = __uint_as_float(ph & 0xFFFF0000u);
        unsigned int pl = cvtpk_bf16(v0 - h0, v1 - h1);
        hp[i] = ph; lp[i] = pl;
    }
}

// Decode index u in [0,25) -> (i, d), i,d in [0,7), i+d even.
__device__ __forceinline__ void dec25(int u, int& i, int& d) {
    int ii = (u >= 4) + (u >= 7) + (u >= 11) + (u >= 14) + (u >= 18) + (u >= 21);
    int cum = (7 * ii + 1) >> 1;
    i = ii;
    d = 2 * (u - cum) + (ii & 1);
}
// Encode (i,d) -> [0,25), inverse of dec25.
__device__ __forceinline__ int enc25(int i, int d) {
    return ((7 * i + 1) >> 1) + ((d - (i & 1)) >> 1);
}

// Compact index a in [0,640) -> flat column into W1's FLAT dim (a>=625 unused).
__device__ __forceinline__ int kflat_of(int a) {
    int ar = a / 25, ac = a % 25;
    int i, dy, j, dx;
    dec25(ar, i, dy);
    dec25(ac, j, dx);
    int pi = (dy + 16 - i) >> 1;
    int pj = (dx + 16 - j) >> 1;
    return (pi * 16 + pj) * 49 + i * 7 + j;
}

#define MM(d, a, b) d = __builtin_amdgcn_mfma_f32_16x16x32_bf16(a, b, d, 0, 0, 0)

// ---------------------------------------------------------------------------
// MEGA kernel (EXACT R14 revert — best measured config): corr parity Gram +
// W1/W2 prep fused, interleaved routing, 2-deep dbuf global_load_lds with
// counted vmcnt.
// ---------------------------------------------------------------------------
__global__ __launch_bounds__(256) void corr_prep_kernel(
    const float* __restrict__ p1, const float* __restrict__ p2,
    const float* __restrict__ W1, const float* __restrict__ W2,
    unsigned short* __restrict__ xh, unsigned short* __restrict__ xl,
    unsigned short* __restrict__ w1h, unsigned short* __restrict__ w1l,
    unsigned short* __restrict__ w2h, unsigned short* __restrict__ w2l)
{
    __shared__ float4 Tb[2][2][512];       // [buf][tensor][8*64] = 32 KB
    __shared__ unsigned short SXh[KPAD];   // compact output staging
    __shared__ unsigned short SXl[KPAD];

    const int bid = blockIdx.x;
    const int t   = threadIdx.x;

    bool isCorr = false;
    int cid = 0, pid = 0;
    if (bid < 2048) {
        if ((bid & 1) == 0) { isCorr = true; cid = bid >> 1; }
        else                { pid = bid >> 1; }
    } else {
        pid = 1024 + (bid - 2048);
    }

    if (!isCorr) {
        // ---- weight prep branch (block-uniform) ----
        if (pid < 2560) {
            int idx = pid * 256 + t;             // over REP_N*KPAD
            int n = idx / KPAD, a = idx - n * KPAD;
            float v = 0.f;
            if (a < KVALID) v = W1[(size_t)n * SP + kflat_of(a)];
            unsigned short h, l;
            split2(v, h, l);
            w1h[idx] = h; w1l[idx] = l;
        } else {
            int idx = ((pid - 2560) * 256 + t) * 4;   // over REP_N*REP_N
            float4 v = *(const float4*)&W2[idx];
            unsigned short h0, l0, h1, l1, h2, l2, h3, l3;
            split2(v.x, h0, l0); split2(v.y, h1, l1);
            split2(v.z, h2, l2); split2(v.w, h3, l3);
            *(ushort4*)&w2h[idx] = make_ushort4(h0, h1, h2, h3);
            *(ushort4*)&w2l[idx] = make_ushort4(l0, l1, l2, l3);
        }
        return;
    }

    // ---- corr branch ----
    const float* P1 = p1 + (size_t)cid * SP;
    const float* P2 = p2 + (size_t)cid * SP;

    const int wv   = t >> 6;
    const int lane = t & 63;
    const int fr   = lane & 15;        // class-pos index (A row / B col)
    const int fg   = (lane >> 4) * 8;  // k-offset within 32-row tile

    // parity-class geometry
    const int ci = wv >> 1, cj = wv & 1;
    const int nj = 4 - cj;
    const int clsN = (4 - ci) * nj;          // 16 / 12 / 12 / 9
    const int pr = (fr < clsN) ? fr : 0;
    const int sPos = (2 * (pr / nj) + ci) * 7 + (2 * (pr % nj) + cj);

    const float* PS = (wv < 2) ? P1 : P2;
    const int tens  = wv >> 1;
    const int start = (wv & 1) * 4;          // bq range [0,4) or [4,8)

    #define STAGE(buf, hc)                                                     \
        do {                                                                   \
            const int off_ = (hc) * 1568;                                      \
            float4* T_ = &Tb[(buf)][tens][0];                                  \
            _Pragma("unroll")                                                  \
            for (int j_ = 0; j_ < 4; ++j_) {                                   \
                const int bq_  = start + j_;                                   \
                const int src_ = min(bq_ * 64 + lane, 391);                    \
                __builtin_amdgcn_global_load_lds(                              \
                    (const __attribute__((address_space(1))) unsigned int*)    \
                        (PS + off_ + src_ * 4),                                \
                    (__attribute__((address_space(3))) unsigned int*)          \
                        (T_ + bq_ * 64),                                       \
                    16, 0, 0);                                                 \
            }                                                                  \
        } while (0)

    // zero output staging (tail 625..639 must be 0)
    for (int i = t; i < KPAD; i += 256) { SXh[i] = 0; SXl[i] = 0; }

    STAGE(0, 0);   // prologue: 2 stages in flight
    STAGE(1, 1);

    f32x4 acc = {};
    #pragma unroll
    for (int hc = 0; hc < 8; ++hc) {
        if (hc < 7) asm volatile("s_waitcnt vmcnt(4)" ::: "memory");
        else        asm volatile("s_waitcnt vmcnt(0)" ::: "memory");
        __builtin_amdgcn_s_barrier();
        __builtin_amdgcn_sched_barrier(0);

        const int cur = hc & 1;
        const float* Tf1 = (const float*)&Tb[cur][0][0];
        const float* Tf2 = (const float*)&Tb[cur][1][0];
        const int kb = fg * RR + sPos;
        float av[8], bv[8];
        #pragma unroll
        for (int i = 0; i < 8; ++i) {
            av[i] = Tf1[kb + i * RR];
            bv[i] = Tf2[kb + i * RR];
        }
        s16x8 ah, al, bh, bl;
        cvt8(av, ah, al);
        cvt8(bv, bh, bl);
        MM(acc, ah, bh);
        MM(acc, ah, bl);
        MM(acc, al, bh);

        __builtin_amdgcn_sched_barrier(0);
        __builtin_amdgcn_s_barrier();
        if (hc < 6) STAGE(cur, hc + 2);
    }
    #undef STAGE

    // Epilogue (verified R9): C/D col = lane&15, row = 4*(lane>>4)+r.
    const int arow = (lane >> 4) * 4;
    if (fr < clsN) {
        const int dy = 2 * (fr / nj) + ci;
        const int dx = 2 * (fr % nj) + cj;
        #pragma unroll
        for (int r = 0; r < 4; ++r) {
            const int rowp = arow + r;
            if (rowp < clsN) {
                const int i1 = 2 * (rowp / nj) + ci;
                const int j1 = 2 * (rowp % nj) + cj;
                const int aidx = enc25(i1, dy) * 25 + enc25(j1, dx);
                unsigned short hh, ll;
                split2(acc[r], hh, ll);
                SXh[aidx] = hh; SXl[aidx] = ll;
            }
        }
    }
    __syncthreads();

    unsigned int* rh = (unsigned int*)(xh + (size_t)cid * KPAD);
    unsigned int* rl = (unsigned int*)(xl + (size_t)cid * KPAD);
    const unsigned int* sh = (const unsigned int*)SXh;
    const unsigned int* sl = (const unsigned int*)SXl;
    for (int i = t; i < KPAD / 2; i += 256) { rh[i] = sh[i]; rl[i] = sl[i]; }
}

// ---------------------------------------------------------------------------
// MFMA GEMM: Y[m,n] = relu( sum_k X[m,k]*W[n,k] + bias[n] )
// X,W as bf16 hi/lo planes; products hh + hl + lh. 64x32 tile, BK=64,
// grid (N/32, M/64) = 512 blocks. 4 waves, each 32x16.
// HEAD_FUSE: instead of writing Y, accumulate out[row,o] += v*W3[o,col]
// via 16-lane shuffle reduction + one atomicAdd per (row,o,wave).
// ---------------------------------------------------------------------------
template<bool SPLIT_OUT, bool HEAD_FUSE>
__global__ __launch_bounds__(256) void gemm_mfma(
    const unsigned short* __restrict__ Xh, const unsigned short* __restrict__ Xl, int ldx,
    const unsigned short* __restrict__ Wh, const unsigned short* __restrict__ Wl, int ldw,
    const float* __restrict__ bias, int K,
    unsigned short* __restrict__ Yh, unsigned short* __restrict__ Yl, int ldy,
    const float* __restrict__ W3, const float* __restrict__ b3,
    float* __restrict__ out)
{
    __shared__ unsigned short As[2][64][72];   // 18.4 KB
    __shared__ unsigned short Bs[2][32][72];   // 9.2 KB

    const int t = threadIdx.x;
    const int m_base = blockIdx.y * 64;
    const int n_base = blockIdx.x * 32;

    const int trow = t >> 2;          // 0..63  (A rows)
    const int tc   = (t & 3) * 8;     // 0,8,16,24
    const int trB  = t >> 3;          // 0..31  (B rows)
    const int tcB  = (t & 7) * 8;     // 0..56

    const unsigned short* xh_p = Xh + (size_t)(m_base + trow) * ldx + tc;
    const unsigned short* xl_p = Xl + (size_t)(m_base + trow) * ldx + tc;
    const unsigned short* wh_p = Wh + (size_t)(n_base + trB) * ldw + tcB;
    const unsigned short* wl_p = Wl + (size_t)(n_base + trB) * ldw + tcB;

    const int wv   = t >> 6;
    const int lane = t & 63;
    const int wr = (wv >> 1) * 32;    // 0 or 32
    const int wc = (wv & 1) * 16;     // 0 or 16
    const int fr = lane & 15;
    const int fg = (lane >> 4) * 8;

    f32x4 acc0 = {}, acc1 = {};

    for (int k0 = 0; k0 < K; k0 += 64) {
        s16x8 vxh0 = *(const s16x8*)(xh_p + k0);
        s16x8 vxh1 = *(const s16x8*)(xh_p + k0 + 32);
        s16x8 vxl0 = *(const s16x8*)(xl_p + k0);
        s16x8 vxl1 = *(const s16x8*)(xl_p + k0 + 32);
        s16x8 vwh  = *(const s16x8*)(wh_p + k0);
        s16x8 vwl  = *(const s16x8*)(wl_p + k0);
        __syncthreads();
        *(s16x8*)&As[0][trow][tc]      = vxh0;
        *(s16x8*)&As[0][trow][tc + 32] = vxh1;
        *(s16x8*)&As[1][trow][tc]      = vxl0;
        *(s16x8*)&As[1][trow][tc + 32] = vxl1;
        *(s16x8*)&Bs[0][trB][tcB]      = vwh;
        *(s16x8*)&Bs[1][trB][tcB]      = vwl;
        __syncthreads();

        #pragma unroll
        for (int ks = 0; ks < 2; ++ks) {
            const int ko = ks * 32 + fg;
            s16x8 ah0 = *(const s16x8*)&As[0][wr + fr][ko];
            s16x8 ah1 = *(const s16x8*)&As[0][wr + 16 + fr][ko];
            s16x8 al0 = *(const s16x8*)&As[1][wr + fr][ko];
            s16x8 al1 = *(const s16x8*)&As[1][wr + 16 + fr][ko];
            s16x8 bh  = *(const s16x8*)&Bs[0][wc + fr][ko];
            s16x8 bl  = *(const s16x8*)&Bs[1][wc + fr][ko];

            MM(acc0, ah0, bh); MM(acc0, ah0, bl); MM(acc0, al0, bh);
            MM(acc1, ah1, bh); MM(acc1, ah1, bl); MM(acc1, al1, bh);
        }
    }

    const int arow = (lane >> 4) * 4;
    const int col = n_base + wc + fr;
    const float bv = bias[col];
    // head weights for this column (HEAD_FUSE only; W3 is 16 KB, cache-hot)
    float w3v[4];
    if (HEAD_FUSE) {
        #pragma unroll
        for (int o = 0; o < 4; ++o) w3v[o] = W3[o * REP_N + col];
    }
    #pragma unroll
    for (int mf = 0; mf < 2; ++mf) {
        const f32x4 a = mf == 0 ? acc0 : acc1;
        #pragma unroll
        for (int r = 0; r < 4; ++r) {
            const int row = m_base + wr + mf * 16 + arow + r;
            float v = fmaxf(a[r] + bv, 0.f);
            if (SPLIT_OUT) {
                unsigned short h, l;
                split2(v, h, l);
                Yh[(size_t)row * ldy + col] = h;
                Yl[(size_t)row * ldy + col] = l;
            }
            if (HEAD_FUSE) {
                #pragma unroll
                for (int o = 0; o < 4; ++o) {
                    float s = v * w3v[o];
                    // reduce over the 16 fr-lanes sharing this row
                    s += __shfl_xor(s, 1);
                    s += __shfl_xor(s, 2);
                    s += __shfl_xor(s, 4);
                    s += __shfl_xor(s, 8);
                    if (fr == 0) {
                        if (n_base == 0 && wc == 0) s += b3[o];
                        atomicAdd(&out[row * 4 + o], s);
                    }
                }
            }
        }
    }
}

extern "C" void kernel_launch(void* const* d_in, const int* in_sizes, int n_in,
                              void* d_out, int out_size, void* d_ws, size_t ws_size,
                              hipStream_t stream) {
    const float* p1 = (const float*)d_in[0];
    const float* p2 = (const float*)d_in[1];
    const float* W1 = (const float*)d_in[2];
    const float* b1 = (const float*)d_in[3];
    const float* W2 = (const float*)d_in[4];
    const float* b2 = (const float*)d_in[5];
    const float* W3 = (const float*)d_in[6];
    const float* b3 = (const float*)d_in[7];
    float* out = (float*)d_out;

    char* ws = (char*)d_ws;
    unsigned short* xh  = (unsigned short*)(ws + 0);         // 1.31 MB
    unsigned short* xl  = (unsigned short*)(ws + 1310720);   // 1.31 MB
    unsigned short* w1h = (unsigned short*)(ws + 2621440);   // 1.31 MB
    unsigned short* w1l = (unsigned short*)(ws + 3932160);   // 1.31 MB
    unsigned short* h1h = (unsigned short*)(ws + 5242880);   // 2.10 MB
    unsigned short* h1l = (unsigned short*)(ws + 7340032);   // 2.10 MB
    unsigned short* w2h = (unsigned short*)(ws + 9437184);   // 2.10 MB
    unsigned short* w2l = (unsigned short*)(ws + 11534336);  // 2.10 MB

    // out accumulates atomically in GEMM2's epilogue: zero it first
    hipMemsetAsync(out, 0, (size_t)out_size * sizeof(float), stream);

    // Fused corr + weight-prep (R14 config — best measured)
    corr_prep_kernel<<<4608, 256, 0, stream>>>(
        p1, p2, W1, W2, xh, xl, w1h, w1l, w2h, w2l);

    // GEMM1: h1 = relu(x @ W1g.T + b1), split output planes
    gemm_mfma<true, false><<<dim3(32, 16), 256, 0, stream>>>(
        xh, xl, KPAD, w1h, w1l, KPAD, b1, KPAD,
        h1h, h1l, REP_N,
        (const float*)nullptr, (const float*)nullptr, (float*)nullptr);

    // GEMM2 + fused head: out = relu(h1 @ W2.T + b2) @ W3.T + b3
    gemm_mfma<false, true><<<dim3(32, 16), 256, 0, stream>>>(
        h1h, h1l, REP_N, w2h, w2l, REP_N, b2, REP_N,
        (unsigned short*)nullptr, (unsigned short*)nullptr, REP_N,
        W3, b3, out);
}

// Round 17
// 61.921 us; speedup vs baseline: 1.7849x; 1.7849x over previous
//
#include <hip/hip_runtime.h>

// Problem constants
#define BATCH 1024
#define RR    49        // 7*7 spatial
#define SP    12544     // 256*49 per-batch patch elems; also FLAT
#define KVALID 625      // nonzero correlation outputs per batch
#define KPAD   640      // padded K for GEMM1
#define REP_N  1024

typedef __attribute__((ext_vector_type(4))) float f32x4;
typedef __attribute__((ext_vector_type(8))) short s16x8;   // 8 bf16 (4 VGPRs)

// ---- bf16 split helpers (RNE) ----
__device__ __forceinline__ unsigned short f2bf_rne(float f) {
    unsigned int u = __float_as_uint(f);
    unsigned int r = u + 0x7FFFu + ((u >> 16) & 1u);
    return (unsigned short)(r >> 16);
}
__device__ __forceinline__ float bf2f(unsigned short h) {
    return __uint_as_float(((unsigned int)h) << 16);
}
__device__ __forceinline__ void split2(float v, unsigned short& h, unsigned short& l) {
    h = f2bf_rne(v);
    l = f2bf_rne(v - bf2f(h));
}
// Pack two floats to bf16 pair (verified numerically R4-R16).
__device__ __forceinline__ unsigned int cvtpk_bf16(float a, float b) {
    unsigned int r;
    asm("v_cvt_pk_bf16_f32 %0, %1, %2" : "=v"(r) : "v"(a), "v"(b));
    return r;
}
// Split 8 floats -> hi/lo s16x8 fragments.
__device__ __forceinline__ void cvt8(const float* v, s16x8& hv, s16x8& lv) {
    unsigned int* hp = (unsigned int*)&hv;
    unsigned int* lp = (unsigned int*)&lv;
    #pragma unroll
    for (int i = 0; i < 4; ++i) {
        float v0 = v[2 * i], v1 = v[2 * i + 1];
        unsigned int ph = cvtpk_bf16(v0, v1);
        float h0 = __uint_as_float(ph << 16);
        float h1 = __uint_as_float(ph & 0xFFFF0000u);
        unsigned int pl = cvtpk_bf16(v0 - h0, v1 - h1);
        hp[i] = ph; lp[i] = pl;
    }
}

// Decode index u in [0,25) -> (i, d), i,d in [0,7), i+d even.
__device__ __forceinline__ void dec25(int u, int& i, int& d) {
    int ii = (u >= 4) + (u >= 7) + (u >= 11) + (u >= 14) + (u >= 18) + (u >= 21);
    int cum = (7 * ii + 1) >> 1;
    i = ii;
    d = 2 * (u - cum) + (ii & 1);
}
// Encode (i,d) -> [0,25), inverse of dec25.
__device__ __forceinline__ int enc25(int i, int d) {
    return ((7 * i + 1) >> 1) + ((d - (i & 1)) >> 1);
}

// Compact index a in [0,640) -> flat column into W1's FLAT dim (a>=625 unused).
__device__ __forceinline__ int kflat_of(int a) {
    int ar = a / 25, ac = a % 25;
    int i, dy, j, dx;
    dec25(ar, i, dy);
    dec25(ac, j, dx);
    int pi = (dy + 16 - i) >> 1;
    int pj = (dx + 16 - j) >> 1;
    return (pi * 16 + pj) * 49 + i * 7 + j;
}

#define MM(d, a, b) d = __builtin_amdgcn_mfma_f32_16x16x32_bf16(a, b, d, 0, 0, 0)

// ---------------------------------------------------------------------------
// MEGA kernel: corr (parity Gram, verified R9/R12) + W1/W2 prep fused.
// Block routing (interleaved): bid<2048 even -> corr batch bid/2; odd ->
// W1-prep bid/2; bid>=2048 -> prep 1024+(bid-2048).
// corr: 8 half-chunks (32 ch) double-buffered via global_load_lds width=16
// with COUNTED vmcnt (T4): per phase wait vmcnt(4) — only the current
// buffer's 4 loads — the next buffer's loads STAY IN FLIGHT across the
// barrier. No vmcnt(0) drain until the final phase. Raw s_barrier pairs
// replace __syncthreads.
// ---------------------------------------------------------------------------
__global__ __launch_bounds__(256) void corr_prep_kernel(
    const float* __restrict__ p1, const float* __restrict__ p2,
    const float* __restrict__ W1, const float* __restrict__ W2,
    unsigned short* __restrict__ xh, unsigned short* __restrict__ xl,
    unsigned short* __restrict__ w1h, unsigned short* __restrict__ w1l,
    unsigned short* __restrict__ w2h, unsigned short* __restrict__ w2l)
{
    __shared__ float4 Tb[2][2][512];       // [buf][tensor][8*64] = 32 KB
    __shared__ unsigned short SXh[KPAD];   // compact output staging
    __shared__ unsigned short SXl[KPAD];

    const int bid = blockIdx.x;
    const int t   = threadIdx.x;

    bool isCorr = false;
    int cid = 0, pid = 0;
    if (bid < 2048) {
        if ((bid & 1) == 0) { isCorr = true; cid = bid >> 1; }
        else                { pid = bid >> 1; }
    } else {
        pid = 1024 + (bid - 2048);
    }

    if (!isCorr) {
        // ---- weight prep branch (block-uniform) ----
        if (pid < 2560) {
            int idx = pid * 256 + t;             // over REP_N*KPAD
            int n = idx / KPAD, a = idx - n * KPAD;
            float v = 0.f;
            if (a < KVALID) v = W1[(size_t)n * SP + kflat_of(a)];
            unsigned short h, l;
            split2(v, h, l);
            w1h[idx] = h; w1l[idx] = l;
        } else {
            int idx = ((pid - 2560) * 256 + t) * 4;   // over REP_N*REP_N
            float4 v = *(const float4*)&W2[idx];
            unsigned short h0, l0, h1, l1, h2, l2, h3, l3;
            split2(v.x, h0, l0); split2(v.y, h1, l1);
            split2(v.z, h2, l2); split2(v.w, h3, l3);
            *(ushort4*)&w2h[idx] = make_ushort4(h0, h1, h2, h3);
            *(ushort4*)&w2l[idx] = make_ushort4(l0, l1, l2, l3);
        }
        return;
    }

    // ---- corr branch ----
    const float* P1 = p1 + (size_t)cid * SP;
    const float* P2 = p2 + (size_t)cid * SP;

    const int wv   = t >> 6;
    const int lane = t & 63;
    const int fr   = lane & 15;        // class-pos index (A row / B col)
    const int fg   = (lane >> 4) * 8;  // k-offset within 32-row tile

    // parity-class geometry
    const int ci = wv >> 1, cj = wv & 1;
    const int nj = 4 - cj;
    const int clsN = (4 - ci) * nj;          // 16 / 12 / 12 / 9
    const int pr = (fr < clsN) ? fr : 0;
    const int sPos = (2 * (pr / nj) + ci) * 7 + (2 * (pr % nj) + cj);

    // staging role: waves 0,1 -> p1; waves 2,3 -> p2. Half-chunk = 32ch*49
    // = 1568 floats = 392 float4; each wave issues a UNIFORM 4 loads
    // (regions of 64 float4; bq 6 partial and bq 7 dummy are src-clamped,
    // landing in the LDS pad [392,512)) so vmcnt counts are wave-uniform.
    const float* PS = (wv < 2) ? P1 : P2;
    const int tens  = wv >> 1;
    const int start = (wv & 1) * 4;          // bq range [0,4) or [4,8)

    #define STAGE(buf, hc)                                                     \
        do {                                                                   \
            const int off_ = (hc) * 1568;                                      \
            float4* T_ = &Tb[(buf)][tens][0];                                  \
            _Pragma("unroll")                                                  \
            for (int j_ = 0; j_ < 4; ++j_) {                                   \
                const int bq_  = start + j_;                                   \
                const int src_ = min(bq_ * 64 + lane, 391);                    \
                __builtin_amdgcn_global_load_lds(                              \
                    (const __attribute__((address_space(1))) unsigned int*)    \
                        (PS + off_ + src_ * 4),                                \
                    (__attribute__((address_space(3))) unsigned int*)          \
                        (T_ + bq_ * 64),                                       \
                    16, 0, 0);                                                 \
            }                                                                  \
        } while (0)

    // zero output staging (tail 625..639 must be 0)
    for (int i = t; i < KPAD; i += 256) { SXh[i] = 0; SXl[i] = 0; }

    STAGE(0, 0);   // prologue: 2 stages in flight
    STAGE(1, 1);

    f32x4 acc = {};
    #pragma unroll
    for (int hc = 0; hc < 8; ++hc) {
        // Wait ONLY for the current buffer's 4 loads (oldest in the queue);
        // the next buffer's 4 remain outstanding across the barrier.
        if (hc < 7) asm volatile("s_waitcnt vmcnt(4)" ::: "memory");
        else        asm volatile("s_waitcnt vmcnt(0)" ::: "memory");
        __builtin_amdgcn_s_barrier();          // all waves' current loads landed
        __builtin_amdgcn_sched_barrier(0);     // pin: no ds_read hoisted above

        const int cur = hc & 1;
        const float* Tf1 = (const float*)&Tb[cur][0][0];
        const float* Tf2 = (const float*)&Tb[cur][1][0];
        const int kb = fg * RR + sPos;
        float av[8], bv[8];
        #pragma unroll
        for (int i = 0; i < 8; ++i) {
            av[i] = Tf1[kb + i * RR];
            bv[i] = Tf2[kb + i * RR];
        }
        s16x8 ah, al, bh, bl;
        cvt8(av, ah, al);
        cvt8(bv, bh, bl);
        MM(acc, ah, bh);
        MM(acc, ah, bl);
        MM(acc, al, bh);

        __builtin_amdgcn_sched_barrier(0);
        __builtin_amdgcn_s_barrier();          // all waves done reading buf[cur]
        if (hc < 6) STAGE(cur, hc + 2);        // refill the buffer just freed
    }
    #undef STAGE

    // Epilogue (verified R9): C/D col = lane&15, row = 4*(lane>>4)+r.
    const int arow = (lane >> 4) * 4;
    if (fr < clsN) {
        const int dy = 2 * (fr / nj) + ci;
        const int dx = 2 * (fr % nj) + cj;
        #pragma unroll
        for (int r = 0; r < 4; ++r) {
            const int rowp = arow + r;
            if (rowp < clsN) {
                const int i1 = 2 * (rowp / nj) + ci;
                const int j1 = 2 * (rowp % nj) + cj;
                const int aidx = enc25(i1, dy) * 25 + enc25(j1, dx);
                unsigned short hh, ll;
                split2(acc[r], hh, ll);
                SXh[aidx] = hh; SXl[aidx] = ll;
            }
        }
    }
    __syncthreads();

    unsigned int* rh = (unsigned int*)(xh + (size_t)cid * KPAD);
    unsigned int* rl = (unsigned int*)(xl + (size_t)cid * KPAD);
    const unsigned int* sh = (const unsigned int*)SXh;
    const unsigned int* sl = (const unsigned int*)SXl;
    for (int i = t; i < KPAD / 2; i += 256) { rh[i] = sh[i]; rl[i] = sl[i]; }
}

// ---------------------------------------------------------------------------
// MFMA GEMM: Y[m,n] = relu( sum_k X[m,k]*W[n,k] + bias[n] )
// X,W as bf16 hi/lo planes; products hh + hl + lh. 64x32 tile, BK=64,
// grid (N/32, M/64) = 512 blocks -> 2 blocks/CU. 4 waves, each 32x16.
// ---------------------------------------------------------------------------
template<bool SPLIT_OUT>
__global__ __launch_bounds__(256) void gemm_mfma(
    const unsigned short* __restrict__ Xh, const unsigned short* __restrict__ Xl, int ldx,
    const unsigned short* __restrict__ Wh, const unsigned short* __restrict__ Wl, int ldw,
    const float* __restrict__ bias, int K,
    float* __restrict__ Yf, unsigned short* __restrict__ Yh, unsigned short* __restrict__ Yl,
    int ldy)
{
    __shared__ unsigned short As[2][64][72];   // 18.4 KB
    __shared__ unsigned short Bs[2][32][72];   // 9.2 KB

    const int t = threadIdx.x;
    const int m_base = blockIdx.y * 64;
    const int n_base = blockIdx.x * 32;

    const int trow = t >> 2;          // 0..63  (A rows)
    const int tc   = (t & 3) * 8;     // 0,8,16,24
    const int trB  = t >> 3;          // 0..31  (B rows)
    const int tcB  = (t & 7) * 8;     // 0..56

    const unsigned short* xh_p = Xh + (size_t)(m_base + trow) * ldx + tc;
    const unsigned short* xl_p = Xl + (size_t)(m_base + trow) * ldx + tc;
    const unsigned short* wh_p = Wh + (size_t)(n_base + trB) * ldw + tcB;
    const unsigned short* wl_p = Wl + (size_t)(n_base + trB) * ldw + tcB;

    const int wv   = t >> 6;
    const int lane = t & 63;
    const int wr = (wv >> 1) * 32;    // 0 or 32
    const int wc = (wv & 1) * 16;     // 0 or 16
    const int fr = lane & 15;
    const int fg = (lane >> 4) * 8;

    f32x4 acc0 = {}, acc1 = {};

    for (int k0 = 0; k0 < K; k0 += 64) {
        s16x8 vxh0 = *(const s16x8*)(xh_p + k0);
        s16x8 vxh1 = *(const s16x8*)(xh_p + k0 + 32);
        s16x8 vxl0 = *(const s16x8*)(xl_p + k0);
        s16x8 vxl1 = *(const s16x8*)(xl_p + k0 + 32);
        s16x8 vwh  = *(const s16x8*)(wh_p + k0);
        s16x8 vwl  = *(const s16x8*)(wl_p + k0);
        __syncthreads();
        *(s16x8*)&As[0][trow][tc]      = vxh0;
        *(s16x8*)&As[0][trow][tc + 32] = vxh1;
        *(s16x8*)&As[1][trow][tc]      = vxl0;
        *(s16x8*)&As[1][trow][tc + 32] = vxl1;
        *(s16x8*)&Bs[0][trB][tcB]      = vwh;
        *(s16x8*)&Bs[1][trB][tcB]      = vwl;
        __syncthreads();

        #pragma unroll
        for (int ks = 0; ks < 2; ++ks) {
            const int ko = ks * 32 + fg;
            s16x8 ah0 = *(const s16x8*)&As[0][wr + fr][ko];
            s16x8 ah1 = *(const s16x8*)&As[0][wr + 16 + fr][ko];
            s16x8 al0 = *(const s16x8*)&As[1][wr + fr][ko];
            s16x8 al1 = *(const s16x8*)&As[1][wr + 16 + fr][ko];
            s16x8 bh  = *(const s16x8*)&Bs[0][wc + fr][ko];
            s16x8 bl  = *(const s16x8*)&Bs[1][wc + fr][ko];

            MM(acc0, ah0, bh); MM(acc0, ah0, bl); MM(acc0, al0, bh);
            MM(acc1, ah1, bh); MM(acc1, ah1, bl); MM(acc1, al1, bh);
        }
    }

    const int arow = (lane >> 4) * 4;
    const int col = n_base + wc + fr;
    const float bv = bias[col];
    #pragma unroll
    for (int mf = 0; mf < 2; ++mf) {
        const f32x4 a = mf == 0 ? acc0 : acc1;
        #pragma unroll
        for (int r = 0; r < 4; ++r) {
            const int row = m_base + wr + mf * 16 + arow + r;
            float v = fmaxf(a[r] + bv, 0.f);
            if (SPLIT_OUT) {
                unsigned short h, l;
                split2(v, h, l);
                Yh[(size_t)row * ldy + col] = h;
                Yl[(size_t)row * ldy + col] = l;
            } else {
                Yf[(size_t)row * ldy + col] = v;
            }
        }
    }
}

// ---------------------------------------------------------------------------
// Head: out[b,:] = h2[b,:] @ W3.T + b3
// ---------------------------------------------------------------------------
__global__ __launch_bounds__(256) void head_kernel(
    const float* __restrict__ h2, const float* __restrict__ W3,
    const float* __restrict__ b3, float* __restrict__ out)
{
    const int b = blockIdx.x;
    const int t = threadIdx.x;
    const float* row = h2 + (size_t)b * REP_N;

    float a0 = 0.f, a1 = 0.f, a2 = 0.f, a3 = 0.f;
    for (int k = t; k < REP_N; k += 256) {
        float x = row[k];
        a0 = fmaf(x, W3[k],             a0);
        a1 = fmaf(x, W3[REP_N + k],     a1);
        a2 = fmaf(x, W3[2 * REP_N + k], a2);
        a3 = fmaf(x, W3[3 * REP_N + k], a3);
    }
    #pragma unroll
    for (int off = 32; off > 0; off >>= 1) {
        a0 += __shfl_down(a0, off);
        a1 += __shfl_down(a1, off);
        a2 += __shfl_down(a2, off);
        a3 += __shfl_down(a3, off);
    }
    __shared__ float red[4][4];
    int wid = t >> 6, lane = t & 63;
    if (lane == 0) { red[wid][0] = a0; red[wid][1] = a1; red[wid][2] = a2; red[wid][3] = a3; }
    __syncthreads();
    if (t < 4) {
        out[b * 4 + t] = red[0][t] + red[1][t] + red[2][t] + red[3][t] + b3[t];
    }
}

extern "C" void kernel_launch(void* const* d_in, const int* in_sizes, int n_in,
                              void* d_out, int out_size, void* d_ws, size_t ws_size,
                              hipStream_t stream) {
    const float* p1 = (const float*)d_in[0];
    const float* p2 = (const float*)d_in[1];
    const float* W1 = (const float*)d_in[2];
    const float* b1 = (const float*)d_in[3];
    const float* W2 = (const float*)d_in[4];
    const float* b2 = (const float*)d_in[5];
    const float* W3 = (const float*)d_in[6];
    const float* b3 = (const float*)d_in[7];
    float* out = (float*)d_out;

    char* ws = (char*)d_ws;
    unsigned short* xh  = (unsigned short*)(ws + 0);         // 1.31 MB
    unsigned short* xl  = (unsigned short*)(ws + 1310720);   // 1.31 MB
    unsigned short* w1h = (unsigned short*)(ws + 2621440);   // 1.31 MB
    unsigned short* w1l = (unsigned short*)(ws + 3932160);   // 1.31 MB
    float*          h2  = (float*)(ws + 0);                  // 4.19 MB (reuse after GEMM1)
    unsigned short* h1h = (unsigned short*)(ws + 5242880);   // 2.10 MB
    unsigned short* h1l = (unsigned short*)(ws + 7340032);   // 2.10 MB
    unsigned short* w2h = (unsigned short*)(ws + 9437184);   // 2.10 MB
    unsigned short* w2l = (unsigned short*)(ws + 11534336);  // 2.10 MB

    // Fused corr + weight-prep (interleaved block routing, counted-vmcnt corr)
    corr_prep_kernel<<<4608, 256, 0, stream>>>(
        p1, p2, W1, W2, xh, xl, w1h, w1l, w2h, w2l);

    // GEMM1: h1 = relu(x @ W1g.T + b1), split output planes
    gemm_mfma<true><<<dim3(32, 16), 256, 0, stream>>>(
        xh, xl, KPAD, w1h, w1l, KPAD, b1, KPAD,
        (float*)nullptr, h1h, h1l, REP_N);

    // GEMM2: h2 = relu(h1 @ W2.T + b2), f32 output
    gemm_mfma<false><<<dim3(32, 16), 256, 0, stream>>>(
        h1h, h1l, REP_N, w2h, w2l, REP_N, b2, REP_N,
        h2, (unsigned short*)nullptr, (unsigned short*)nullptr, REP_N);

    head_kernel<<<BATCH, 256, 0, stream>>>(h2, W3, b3, out);
}

// Round 18
// 61.422 us; speedup vs baseline: 1.7994x; 1.0081x over previous
//
#include <hip/hip_runtime.h>

// Problem constants
#define BATCH 1024
#define RR    49        // 7*7 spatial
#define SP    12544     // 256*49 per-batch patch elems; also FLAT
#define KVALID 625      // nonzero correlation outputs per batch
#define KPAD   640      // padded K for GEMM1
#define REP_N  1024

typedef __attribute__((ext_vector_type(4))) float f32x4;
typedef __attribute__((ext_vector_type(8))) short s16x8;   // 8 bf16 (4 VGPRs)

// ---- bf16 split helpers (RNE) ----
__device__ __forceinline__ unsigned short f2bf_rne(float f) {
    unsigned int u = __float_as_uint(f);
    unsigned int r = u + 0x7FFFu + ((u >> 16) & 1u);
    return (unsigned short)(r >> 16);
}
__device__ __forceinline__ float bf2f(unsigned short h) {
    return __uint_as_float(((unsigned int)h) << 16);
}
__device__ __forceinline__ void split2(float v, unsigned short& h, unsigned short& l) {
    h = f2bf_rne(v);
    l = f2bf_rne(v - bf2f(h));
}
// Pack two floats to bf16 pair (verified numerically R4-R17).
__device__ __forceinline__ unsigned int cvtpk_bf16(float a, float b) {
    unsigned int r;
    asm("v_cvt_pk_bf16_f32 %0, %1, %2" : "=v"(r) : "v"(a), "v"(b));
    return r;
}
// Split 8 floats -> hi/lo s16x8 fragments.
__device__ __forceinline__ void cvt8(const float* v, s16x8& hv, s16x8& lv) {
    unsigned int* hp = (unsigned int*)&hv;
    unsigned int* lp = (unsigned int*)&lv;
    #pragma unroll
    for (int i = 0; i < 4; ++i) {
        float v0 = v[2 * i], v1 = v[2 * i + 1];
        unsigned int ph = cvtpk_bf16(v0, v1);
        float h0 = __uint_as_float(ph << 16);
        float h1 = __uint_as_float(ph & 0xFFFF0000u);
        unsigned int pl = cvtpk_bf16(v0 - h0, v1 - h1);
        hp[i] = ph; lp[i] = pl;
    }
}

// Decode index u in [0,25) -> (i, d), i,d in [0,7), i+d even.
__device__ __forceinline__ void dec25(int u, int& i, int& d) {
    int ii = (u >= 4) + (u >= 7) + (u >= 11) + (u >= 14) + (u >= 18) + (u >= 21);
    int cum = (7 * ii + 1) >> 1;
    i = ii;
    d = 2 * (u - cum) + (ii & 1);
}
// Encode (i,d) -> [0,25), inverse of dec25.
__device__ __forceinline__ int enc25(int i, int d) {
    return ((7 * i + 1) >> 1) + ((d - (i & 1)) >> 1);
}

// Compact index a in [0,640) -> flat column into W1's FLAT dim (a>=625 unused).
__device__ __forceinline__ int kflat_of(int a) {
    int ar = a / 25, ac = a % 25;
    int i, dy, j, dx;
    dec25(ar, i, dy);
    dec25(ac, j, dx);
    int pi = (dy + 16 - i) >> 1;
    int pj = (dx + 16 - j) >> 1;
    return (pi * 16 + pj) * 49 + i * 7 + j;
}

#define MM(d, a, b) d = __builtin_amdgcn_mfma_f32_16x16x32_bf16(a, b, d, 0, 0, 0)

// ---------------------------------------------------------------------------
// MEGA kernel: corr (parity Gram) + W1/W2 prep fused.
// Routing: bid%15==0 -> corr block bid/15 (256 blocks, 4 batches each —
// ONE BATCH PER WAVE, fully independent); else prep pid = bid - bid/15 - 1.
// corr wave: 8 chunks of 32 channels. Per chunk: per-wave vmcnt(0) (no
// barriers anywhere), 64 ds_read_b32 (all 4 parity classes), lgkmcnt fence,
// issue next chunk's 14 global_load_lds (fly under cvt+MFMA), then 8 cvt8 +
// 12 MFMA. Wave-private LDS: [2 tensors][448 f4] staging + private SX slice.
// ---------------------------------------------------------------------------
__global__ __launch_bounds__(256) void corr_prep_kernel(
    const float* __restrict__ p1, const float* __restrict__ p2,
    const float* __restrict__ W1, const float* __restrict__ W2,
    unsigned short* __restrict__ xh, unsigned short* __restrict__ xl,
    unsigned short* __restrict__ w1h, unsigned short* __restrict__ w1l,
    unsigned short* __restrict__ w2h, unsigned short* __restrict__ w2l)
{
    __shared__ float4 Tb[4][2][448];            // per-wave staging, 57.3 KB
    __shared__ unsigned short SXh[4][KPAD];     // per-wave output staging
    __shared__ unsigned short SXl[4][KPAD];     // (10 KB)

    const int bid = blockIdx.x;
    const int t   = threadIdx.x;

    if (bid % 15 != 0) {
        // ---- weight prep branch (block-uniform) ----
        const int pid = bid - bid / 15 - 1;     // 0..3583
        if (pid < 2560) {
            int idx = pid * 256 + t;            // over REP_N*KPAD
            int n = idx / KPAD, a = idx - n * KPAD;
            float v = 0.f;
            if (a < KVALID) v = W1[(size_t)n * SP + kflat_of(a)];
            unsigned short h, l;
            split2(v, h, l);
            w1h[idx] = h; w1l[idx] = l;
        } else {
            int idx = ((pid - 2560) * 256 + t) * 4;   // over REP_N*REP_N
            float4 v = *(const float4*)&W2[idx];
            unsigned short h0, l0, h1, l1, h2, l2, h3, l3;
            split2(v.x, h0, l0); split2(v.y, h1, l1);
            split2(v.z, h2, l2); split2(v.w, h3, l3);
            *(ushort4*)&w2h[idx] = make_ushort4(h0, h1, h2, h3);
            *(ushort4*)&w2l[idx] = make_ushort4(l0, l1, l2, l3);
        }
        return;
    }

    // ---- corr branch: wave wv owns batch cid, no inter-wave coupling ----
    const int wv   = t >> 6;
    const int lane = t & 63;
    const int cid  = (bid / 15) * 4 + wv;
    const float* P1 = p1 + (size_t)cid * SP;
    const float* P2 = p2 + (size_t)cid * SP;

    const int fr = lane & 15;        // class-pos index (A row / B col)
    const int fg = (lane >> 4) * 8;  // k-offset within 32-row tile

    float4* T1 = &Tb[wv][0][0];
    float4* T2 = &Tb[wv][1][0];
    const float* Tf1 = (const float*)T1;
    const float* Tf2 = (const float*)T2;

    // chunk = 32 channels = 1568 floats = 392 float4; 7 loads/tensor
    // (last inst lanes 8..63 src-clamped to 391, land in pad [392,448)).
    #define STAGE(cc)                                                          \
        do {                                                                   \
            const int off_ = (cc) * 1568;                                      \
            _Pragma("unroll")                                                  \
            for (int j_ = 0; j_ < 7; ++j_) {                                   \
                const int src_ = min(j_ * 64 + lane, 391);                     \
                __builtin_amdgcn_global_load_lds(                              \
                    (const __attribute__((address_space(1))) unsigned int*)    \
                        (P1 + off_ + src_ * 4),                                \
                    (__attribute__((address_space(3))) unsigned int*)          \
                        (T1 + j_ * 64),                                        \
                    16, 0, 0);                                                 \
            }                                                                  \
            _Pragma("unroll")                                                  \
            for (int j_ = 0; j_ < 7; ++j_) {                                   \
                const int src_ = min(j_ * 64 + lane, 391);                     \
                __builtin_amdgcn_global_load_lds(                              \
                    (const __attribute__((address_space(1))) unsigned int*)    \
                        (P2 + off_ + src_ * 4),                                \
                    (__attribute__((address_space(3))) unsigned int*)          \
                        (T2 + j_ * 64),                                        \
                    16, 0, 0);                                                 \
            }                                                                  \
        } while (0)

    STAGE(0);   // prologue

    // zero this wave's output staging (tail 625..639 must be 0)
    for (int i = lane; i < KPAD; i += 64) { SXh[wv][i] = 0; SXl[wv][i] = 0; }

    f32x4 acc0 = {}, acc1 = {}, acc2 = {}, acc3 = {};

    for (int cc = 0; cc < 8; ++cc) {
        asm volatile("s_waitcnt vmcnt(0)" ::: "memory");   // per-wave: chunk landed
        __builtin_amdgcn_sched_barrier(0);

        // ds_reads for ALL 4 parity classes into registers
        float av[4][8], bv[4][8];
        #pragma unroll
        for (int c = 0; c < 4; ++c) {
            const int ci = c >> 1, cj = c & 1;
            const int nj = 4 - cj;
            const int clsN = (4 - ci) * nj;
            const int pr = (fr < clsN) ? fr : 0;
            const int sP = (2 * (pr / nj) + ci) * 7 + (2 * (pr % nj) + cj);
            const int kb = fg * RR + sP;
            #pragma unroll
            for (int i = 0; i < 8; ++i) {
                av[c][i] = Tf1[kb + i * RR];
                bv[c][i] = Tf2[kb + i * RR];
            }
        }
        asm volatile("s_waitcnt lgkmcnt(0)" ::: "memory"); // reads done: LDS free
        __builtin_amdgcn_sched_barrier(0);
        if (cc < 7) STAGE(cc + 1);                         // loads fly under compute

        #pragma unroll
        for (int c = 0; c < 4; ++c) {
            s16x8 ah, al, bh, bl;
            cvt8(av[c], ah, al);
            cvt8(bv[c], bh, bl);
            f32x4* ac = (c == 0) ? &acc0 : (c == 1) ? &acc1 : (c == 2) ? &acc2 : &acc3;
            MM(*ac, ah, bh);
            MM(*ac, ah, bl);
            MM(*ac, al, bh);
        }
        __builtin_amdgcn_sched_barrier(0);
    }
    #undef STAGE

    // Epilogue (verified R9 mapping), per-wave, all 4 classes.
    const int arow = (lane >> 4) * 4;
    #pragma unroll
    for (int c = 0; c < 4; ++c) {
        const int ci = c >> 1, cj = c & 1;
        const int nj = 4 - cj;
        const int clsN = (4 - ci) * nj;
        const f32x4 a = (c == 0) ? acc0 : (c == 1) ? acc1 : (c == 2) ? acc2 : acc3;
        if (fr < clsN) {
            const int dy = 2 * (fr / nj) + ci;
            const int dx = 2 * (fr % nj) + cj;
            #pragma unroll
            for (int r = 0; r < 4; ++r) {
                const int rowp = arow + r;
                if (rowp < clsN) {
                    const int i1 = 2 * (rowp / nj) + ci;
                    const int j1 = 2 * (rowp % nj) + cj;
                    const int aidx = enc25(i1, dy) * 25 + enc25(j1, dx);
                    unsigned short hh, ll;
                    split2(a[r], hh, ll);
                    SXh[wv][aidx] = hh; SXl[wv][aidx] = ll;
                }
            }
        }
    }
    asm volatile("s_waitcnt lgkmcnt(0)" ::: "memory");   // scatter writes done
    __builtin_amdgcn_sched_barrier(0);

    unsigned int* rh = (unsigned int*)(xh + (size_t)cid * KPAD);
    unsigned int* rl = (unsigned int*)(xl + (size_t)cid * KPAD);
    const unsigned int* sh = (const unsigned int*)&SXh[wv][0];
    const unsigned int* sl = (const unsigned int*)&SXl[wv][0];
    for (int i = lane; i < KPAD / 2; i += 64) { rh[i] = sh[i]; rl[i] = sl[i]; }
}

// ---------------------------------------------------------------------------
// MFMA GEMM: Y[m,n] = relu( sum_k X[m,k]*W[n,k] + bias[n] )
// X,W as bf16 hi/lo planes; products hh + hl + lh. 64x32 tile, BK=64,
// grid (N/32, M/64) = 512 blocks -> 2 blocks/CU. 4 waves, each 32x16.
// (unchanged from R14/R17 best)
// ---------------------------------------------------------------------------
template<bool SPLIT_OUT>
__global__ __launch_bounds__(256) void gemm_mfma(
    const unsigned short* __restrict__ Xh, const unsigned short* __restrict__ Xl, int ldx,
    const unsigned short* __restrict__ Wh, const unsigned short* __restrict__ Wl, int ldw,
    const float* __restrict__ bias, int K,
    float* __restrict__ Yf, unsigned short* __restrict__ Yh, unsigned short* __restrict__ Yl,
    int ldy)
{
    __shared__ unsigned short As[2][64][72];   // 18.4 KB
    __shared__ unsigned short Bs[2][32][72];   // 9.2 KB

    const int t = threadIdx.x;
    const int m_base = blockIdx.y * 64;
    const int n_base = blockIdx.x * 32;

    const int trow = t >> 2;          // 0..63  (A rows)
    const int tc   = (t & 3) * 8;     // 0,8,16,24
    const int trB  = t >> 3;          // 0..31  (B rows)
    const int tcB  = (t & 7) * 8;     // 0..56

    const unsigned short* xh_p = Xh + (size_t)(m_base + trow) * ldx + tc;
    const unsigned short* xl_p = Xl + (size_t)(m_base + trow) * ldx + tc;
    const unsigned short* wh_p = Wh + (size_t)(n_base + trB) * ldw + tcB;
    const unsigned short* wl_p = Wl + (size_t)(n_base + trB) * ldw + tcB;

    const int wv   = t >> 6;
    const int lane = t & 63;
    const int wr = (wv >> 1) * 32;    // 0 or 32
    const int wc = (wv & 1) * 16;     // 0 or 16
    const int fr = lane & 15;
    const int fg = (lane >> 4) * 8;

    f32x4 acc0 = {}, acc1 = {};

    for (int k0 = 0; k0 < K; k0 += 64) {
        s16x8 vxh0 = *(const s16x8*)(xh_p + k0);
        s16x8 vxh1 = *(const s16x8*)(xh_p + k0 + 32);
        s16x8 vxl0 = *(const s16x8*)(xl_p + k0);
        s16x8 vxl1 = *(const s16x8*)(xl_p + k0 + 32);
        s16x8 vwh  = *(const s16x8*)(wh_p + k0);
        s16x8 vwl  = *(const s16x8*)(wl_p + k0);
        __syncthreads();
        *(s16x8*)&As[0][trow][tc]      = vxh0;
        *(s16x8*)&As[0][trow][tc + 32] = vxh1;
        *(s16x8*)&As[1][trow][tc]      = vxl0;
        *(s16x8*)&As[1][trow][tc + 32] = vxl1;
        *(s16x8*)&Bs[0][trB][tcB]      = vwh;
        *(s16x8*)&Bs[1][trB][tcB]      = vwl;
        __syncthreads();

        #pragma unroll
        for (int ks = 0; ks < 2; ++ks) {
            const int ko = ks * 32 + fg;
            s16x8 ah0 = *(const s16x8*)&As[0][wr + fr][ko];
            s16x8 ah1 = *(const s16x8*)&As[0][wr + 16 + fr][ko];
            s16x8 al0 = *(const s16x8*)&As[1][wr + fr][ko];
            s16x8 al1 = *(const s16x8*)&As[1][wr + 16 + fr][ko];
            s16x8 bh  = *(const s16x8*)&Bs[0][wc + fr][ko];
            s16x8 bl  = *(const s16x8*)&Bs[1][wc + fr][ko];

            MM(acc0, ah0, bh); MM(acc0, ah0, bl); MM(acc0, al0, bh);
            MM(acc1, ah1, bh); MM(acc1, ah1, bl); MM(acc1, al1, bh);
        }
    }

    const int arow = (lane >> 4) * 4;
    const int col = n_base + wc + fr;
    const float bv = bias[col];
    #pragma unroll
    for (int mf = 0; mf < 2; ++mf) {
        const f32x4 a = mf == 0 ? acc0 : acc1;
        #pragma unroll
        for (int r = 0; r < 4; ++r) {
            const int row = m_base + wr + mf * 16 + arow + r;
            float v = fmaxf(a[r] + bv, 0.f);
            if (SPLIT_OUT) {
                unsigned short h, l;
                split2(v, h, l);
                Yh[(size_t)row * ldy + col] = h;
                Yl[(size_t)row * ldy + col] = l;
            } else {
                Yf[(size_t)row * ldy + col] = v;
            }
        }
    }
}

// ---------------------------------------------------------------------------
// Head: out[b,:] = h2[b,:] @ W3.T + b3
// ---------------------------------------------------------------------------
__global__ __launch_bounds__(256) void head_kernel(
    const float* __restrict__ h2, const float* __restrict__ W3,
    const float* __restrict__ b3, float* __restrict__ out)
{
    const int b = blockIdx.x;
    const int t = threadIdx.x;
    const float* row = h2 + (size_t)b * REP_N;

    float a0 = 0.f, a1 = 0.f, a2 = 0.f, a3 = 0.f;
    for (int k = t; k < REP_N; k += 256) {
        float x = row[k];
        a0 = fmaf(x, W3[k],             a0);
        a1 = fmaf(x, W3[REP_N + k],     a1);
        a2 = fmaf(x, W3[2 * REP_N + k], a2);
        a3 = fmaf(x, W3[3 * REP_N + k], a3);
    }
    #pragma unroll
    for (int off = 32; off > 0; off >>= 1) {
        a0 += __shfl_down(a0, off);
        a1 += __shfl_down(a1, off);
        a2 += __shfl_down(a2, off);
        a3 += __shfl_down(a3, off);
    }
    __shared__ float red[4][4];
    int wid = t >> 6, lane = t & 63;
    if (lane == 0) { red[wid][0] = a0; red[wid][1] = a1; red[wid][2] = a2; red[wid][3] = a3; }
    __syncthreads();
    if (t < 4) {
        out[b * 4 + t] = red[0][t] + red[1][t] + red[2][t] + red[3][t] + b3[t];
    }
}

extern "C" void kernel_launch(void* const* d_in, const int* in_sizes, int n_in,
                              void* d_out, int out_size, void* d_ws, size_t ws_size,
                              hipStream_t stream) {
    const float* p1 = (const float*)d_in[0];
    const float* p2 = (const float*)d_in[1];
    const float* W1 = (const float*)d_in[2];
    const float* b1 = (const float*)d_in[3];
    const float* W2 = (const float*)d_in[4];
    const float* b2 = (const float*)d_in[5];
    const float* W3 = (const float*)d_in[6];
    const float* b3 = (const float*)d_in[7];
    float* out = (float*)d_out;

    char* ws = (char*)d_ws;
    unsigned short* xh  = (unsigned short*)(ws + 0);         // 1.31 MB
    unsigned short* xl  = (unsigned short*)(ws + 1310720);   // 1.31 MB
    unsigned short* w1h = (unsigned short*)(ws + 2621440);   // 1.31 MB
    unsigned short* w1l = (unsigned short*)(ws + 3932160);   // 1.31 MB
    float*          h2  = (float*)(ws + 0);                  // 4.19 MB (reuse after GEMM1)
    unsigned short* h1h = (unsigned short*)(ws + 5242880);   // 2.10 MB
    unsigned short* h1l = (unsigned short*)(ws + 7340032);   // 2.10 MB
    unsigned short* w2h = (unsigned short*)(ws + 9437184);   // 2.10 MB
    unsigned short* w2l = (unsigned short*)(ws + 11534336);  // 2.10 MB

    // Fused corr (wave-independent batches) + weight-prep
    corr_prep_kernel<<<3840, 256, 0, stream>>>(
        p1, p2, W1, W2, xh, xl, w1h, w1l, w2h, w2l);

    // GEMM1: h1 = relu(x @ W1g.T + b1), split output planes
    gemm_mfma<true><<<dim3(32, 16), 256, 0, stream>>>(
        xh, xl, KPAD, w1h, w1l, KPAD, b1, KPAD,
        (float*)nullptr, h1h, h1l, REP_N);

    // GEMM2: h2 = relu(h1 @ W2.T + b2), f32 output
    gemm_mfma<false><<<dim3(32, 16), 256, 0, stream>>>(
        h1h, h1l, REP_N, w2h, w2l, REP_N, b2, REP_N,
        h2, (unsigned short*)nullptr, (unsigned short*)nullptr, REP_N);

    head_kernel<<<BATCH, 256, 0, stream>>>(h2, W3, b3, out);
}

// Round 20
// 61.338 us; speedup vs baseline: 1.8018x; 1.0014x over previous
//
#include <hip/hip_runtime.h>

// Problem constants
#define BATCH 1024
#define RR    49        // 7*7 spatial
#define SP    12544     // 256*49 per-batch patch elems; also FLAT
#define KVALID 625      // nonzero correlation outputs per batch
#define KPAD   640      // padded K for GEMM1
#define REP_N  1024

typedef __attribute__((ext_vector_type(4))) float f32x4;
typedef __attribute__((ext_vector_type(8))) short s16x8;   // 8 bf16 (4 VGPRs)

// ---- bf16 split helpers (RNE) ----
__device__ __forceinline__ unsigned short f2bf_rne(float f) {
    unsigned int u = __float_as_uint(f);
    unsigned int r = u + 0x7FFFu + ((u >> 16) & 1u);
    return (unsigned short)(r >> 16);
}
__device__ __forceinline__ float bf2f(unsigned short h) {
    return __uint_as_float(((unsigned int)h) << 16);
}
__device__ __forceinline__ void split2(float v, unsigned short& h, unsigned short& l) {
    h = f2bf_rne(v);
    l = f2bf_rne(v - bf2f(h));
}
// Pack two floats to bf16 pair (verified numerically R4-R18).
__device__ __forceinline__ unsigned int cvtpk_bf16(float a, float b) {
    unsigned int r;
    asm("v_cvt_pk_bf16_f32 %0, %1, %2" : "=v"(r) : "v"(a), "v"(b));
    return r;
}
// Split 8 floats -> hi/lo s16x8 fragments.
__device__ __forceinline__ void cvt8(const float* v, s16x8& hv, s16x8& lv) {
    unsigned int* hp = (unsigned int*)&hv;
    unsigned int* lp = (unsigned int*)&lv;
    #pragma unroll
    for (int i = 0; i < 4; ++i) {
        float v0 = v[2 * i], v1 = v[2 * i + 1];
        unsigned int ph = cvtpk_bf16(v0, v1);
        float h0 = __uint_as_float(ph << 16);
        float h1 = __uint_as_float(ph & 0xFFFF0000u);
        unsigned int pl = cvtpk_bf16(v0 - h0, v1 - h1);
        hp[i] = ph; lp[i] = pl;
    }
}

// Decode index u in [0,25) -> (i, d), i,d in [0,7), i+d even.
__device__ __forceinline__ void dec25(int u, int& i, int& d) {
    int ii = (u >= 4) + (u >= 7) + (u >= 11) + (u >= 14) + (u >= 18) + (u >= 21);
    int cum = (7 * ii + 1) >> 1;
    i = ii;
    d = 2 * (u - cum) + (ii & 1);
}
// Encode (i,d) -> [0,25), inverse of dec25.
__device__ __forceinline__ int enc25(int i, int d) {
    return ((7 * i + 1) >> 1) + ((d - (i & 1)) >> 1);
}

// Compact index a in [0,640) -> flat column into W1's FLAT dim (a>=625 unused).
__device__ __forceinline__ int kflat_of(int a) {
    int ar = a / 25, ac = a % 25;
    int i, dy, j, dx;
    dec25(ar, i, dy);
    dec25(ac, j, dx);
    int pi = (dy + 16 - i) >> 1;
    int pj = (dx + 16 - j) >> 1;
    return (pi * 16 + pj) * 49 + i * 7 + j;
}

#define MM(d, a, b) d = __builtin_amdgcn_mfma_f32_16x16x32_bf16(a, b, d, 0, 0, 0)

// ---------------------------------------------------------------------------
// MEGA kernel: corr (parity Gram, verified R9/R12) + W1/W2 prep fused.
// Block routing (interleaved): bid<2048 even -> corr batch bid/2; odd ->
// W1-prep bid/2; bid>=2048 -> prep 1024+(bid-2048).
// corr: 8 half-chunks (32 ch) double-buffered via global_load_lds width=16
// with COUNTED vmcnt (T4): per phase wait vmcnt(4) — only the current
// buffer's 4 loads — the next buffer's loads STAY IN FLIGHT across the
// barrier. No vmcnt(0) drain until the final phase. Raw s_barrier pairs
// replace __syncthreads.
// ---------------------------------------------------------------------------
__global__ __launch_bounds__(256) void corr_prep_kernel(
    const float* __restrict__ p1, const float* __restrict__ p2,
    const float* __restrict__ W1, const float* __restrict__ W2,
    unsigned short* __restrict__ xh, unsigned short* __restrict__ xl,
    unsigned short* __restrict__ w1h, unsigned short* __restrict__ w1l,
    unsigned short* __restrict__ w2h, unsigned short* __restrict__ w2l)
{
    __shared__ float4 Tb[2][2][512];       // [buf][tensor][8*64] = 32 KB
    __shared__ unsigned short SXh[KPAD];   // compact output staging
    __shared__ unsigned short SXl[KPAD];

    const int bid = blockIdx.x;
    const int t   = threadIdx.x;

    bool isCorr = false;
    int cid = 0, pid = 0;
    if (bid < 2048) {
        if ((bid & 1) == 0) { isCorr = true; cid = bid >> 1; }
        else                { pid = bid >> 1; }
    } else {
        pid = 1024 + (bid - 2048);
    }

    if (!isCorr) {
        // ---- weight prep branch (block-uniform) ----
        if (pid < 2560) {
            int idx = pid * 256 + t;             // over REP_N*KPAD
            int n = idx / KPAD, a = idx - n * KPAD;
            float v = 0.f;
            if (a < KVALID) v = W1[(size_t)n * SP + kflat_of(a)];
            unsigned short h, l;
            split2(v, h, l);
            w1h[idx] = h; w1l[idx] = l;
        } else {
            int idx = ((pid - 2560) * 256 + t) * 4;   // over REP_N*REP_N
            float4 v = *(const float4*)&W2[idx];
            unsigned short h0, l0, h1, l1, h2, l2, h3, l3;
            split2(v.x, h0, l0); split2(v.y, h1, l1);
            split2(v.z, h2, l2); split2(v.w, h3, l3);
            *(ushort4*)&w2h[idx] = make_ushort4(h0, h1, h2, h3);
            *(ushort4*)&w2l[idx] = make_ushort4(l0, l1, l2, l3);
        }
        return;
    }

    // ---- corr branch ----
    const float* P1 = p1 + (size_t)cid * SP;
    const float* P2 = p2 + (size_t)cid * SP;

    const int wv   = t >> 6;
    const int lane = t & 63;
    const int fr   = lane & 15;        // class-pos index (A row / B col)
    const int fg   = (lane >> 4) * 8;  // k-offset within 32-row tile

    // parity-class geometry
    const int ci = wv >> 1, cj = wv & 1;
    const int nj = 4 - cj;
    const int clsN = (4 - ci) * nj;          // 16 / 12 / 12 / 9
    const int pr = (fr < clsN) ? fr : 0;
    const int sPos = (2 * (pr / nj) + ci) * 7 + (2 * (pr % nj) + cj);

    // staging role: waves 0,1 -> p1; waves 2,3 -> p2. Half-chunk = 32ch*49
    // = 1568 floats = 392 float4; each wave issues a UNIFORM 4 loads
    // (regions of 64 float4; bq 6 partial and bq 7 dummy are src-clamped,
    // landing in the LDS pad [392,512)) so vmcnt counts are wave-uniform.
    const float* PS = (wv < 2) ? P1 : P2;
    const int tens  = wv >> 1;
    const int start = (wv & 1) * 4;          // bq range [0,4) or [4,8)

    #define STAGE(buf, hc)                                                     \
        do {                                                                   \
            const int off_ = (hc) * 1568;                                      \
            float4* T_ = &Tb[(buf)][tens][0];                                  \
            _Pragma("unroll")                                                  \
            for (int j_ = 0; j_ < 4; ++j_) {                                   \
                const int bq_  = start + j_;                                   \
                const int src_ = min(bq_ * 64 + lane, 391);                    \
                __builtin_amdgcn_global_load_lds(                              \
                    (const __attribute__((address_space(1))) unsigned int*)    \
                        (PS + off_ + src_ * 4),                                \
                    (__attribute__((address_space(3))) unsigned int*)          \
                        (T_ + bq_ * 64),                                       \
                    16, 0, 0);                                                 \
            }                                                                  \
        } while (0)

    // zero output staging (tail 625..639 must be 0)
    for (int i = t; i < KPAD; i += 256) { SXh[i] = 0; SXl[i] = 0; }

    STAGE(0, 0);   // prologue: 2 stages in flight
    STAGE(1, 1);

    f32x4 acc = {};
    #pragma unroll
    for (int hc = 0; hc < 8; ++hc) {
        // Wait ONLY for the current buffer's 4 loads (oldest in the queue);
        // the next buffer's 4 remain outstanding across the barrier.
        if (hc < 7) asm volatile("s_waitcnt vmcnt(4)" ::: "memory");
        else        asm volatile("s_waitcnt vmcnt(0)" ::: "memory");
        __builtin_amdgcn_s_barrier();          // all waves' current loads landed
        __builtin_amdgcn_sched_barrier(0);     // pin: no ds_read hoisted above

        const int cur = hc & 1;
        const float* Tf1 = (const float*)&Tb[cur][0][0];
        const float* Tf2 = (const float*)&Tb[cur][1][0];
        const int kb = fg * RR + sPos;
        float av[8], bv[8];
        #pragma unroll
        for (int i = 0; i < 8; ++i) {
            av[i] = Tf1[kb + i * RR];
            bv[i] = Tf2[kb + i * RR];
        }
        s16x8 ah, al, bh, bl;
        cvt8(av, ah, al);
        cvt8(bv, bh, bl);
        MM(acc, ah, bh);
        MM(acc, ah, bl);
        MM(acc, al, bh);

        __builtin_amdgcn_sched_barrier(0);
        __builtin_amdgcn_s_barrier();          // all waves done reading buf[cur]
        if (hc < 6) STAGE(cur, hc + 2);        // refill the buffer just freed
    }
    #undef STAGE

    // Epilogue (verified R9): C/D col = lane&15, row = 4*(lane>>4)+r.
    const int arow = (lane >> 4) * 4;
    if (fr < clsN) {
        const int dy = 2 * (fr / nj) + ci;
        const int dx = 2 * (fr % nj) + cj;
        #pragma unroll
        for (int r = 0; r < 4; ++r) {
            const int rowp = arow + r;
            if (rowp < clsN) {
                const int i1 = 2 * (rowp / nj) + ci;
                const int j1 = 2 * (rowp % nj) + cj;
                const int aidx = enc25(i1, dy) * 25 + enc25(j1, dx);
                unsigned short hh, ll;
                split2(acc[r], hh, ll);
                SXh[aidx] = hh; SXl[aidx] = ll;
            }
        }
    }
    __syncthreads();

    unsigned int* rh = (unsigned int*)(xh + (size_t)cid * KPAD);
    unsigned int* rl = (unsigned int*)(xl + (size_t)cid * KPAD);
    const unsigned int* sh = (const unsigned int*)SXh;
    const unsigned int* sl = (const unsigned int*)SXl;
    for (int i = t; i < KPAD / 2; i += 256) { rh[i] = sh[i]; rl[i] = sl[i]; }
}

// ---------------------------------------------------------------------------
// MFMA GEMM: Y[m,n] = relu( sum_k X[m,k]*W[n,k] + bias[n] )
// X,W as bf16 hi/lo planes; products hh + hl + lh. 64x32 tile, BK=64,
// grid (N/32, M/64) = 512 blocks -> 2 blocks/CU. 4 waves, each 32x16.
// ---------------------------------------------------------------------------
template<bool SPLIT_OUT>
__global__ __launch_bounds__(256) void gemm_mfma(
    const unsigned short* __restrict__ Xh, const unsigned short* __restrict__ Xl, int ldx,
    const unsigned short* __restrict__ Wh, const unsigned short* __restrict__ Wl, int ldw,
    const float* __restrict__ bias, int K,
    float* __restrict__ Yf, unsigned short* __restrict__ Yh, unsigned short* __restrict__ Yl,
    int ldy)
{
    __shared__ unsigned short As[2][64][72];   // 18.4 KB
    __shared__ unsigned short Bs[2][32][72];   // 9.2 KB

    const int t = threadIdx.x;
    const int m_base = blockIdx.y * 64;
    const int n_base = blockIdx.x * 32;

    const int trow = t >> 2;          // 0..63  (A rows)
    const int tc   = (t & 3) * 8;     // 0,8,16,24
    const int trB  = t >> 3;          // 0..31  (B rows)
    const int tcB  = (t & 7) * 8;     // 0..56

    const unsigned short* xh_p = Xh + (size_t)(m_base + trow) * ldx + tc;
    const unsigned short* xl_p = Xl + (size_t)(m_base + trow) * ldx + tc;
    const unsigned short* wh_p = Wh + (size_t)(n_base + trB) * ldw + tcB;
    const unsigned short* wl_p = Wl + (size_t)(n_base + trB) * ldw + tcB;

    const int wv   = t >> 6;
    const int lane = t & 63;
    const int wr = (wv >> 1) * 32;    // 0 or 32
    const int wc = (wv & 1) * 16;     // 0 or 16
    const int fr = lane & 15;
    const int fg = (lane >> 4) * 8;

    f32x4 acc0 = {}, acc1 = {};

    for (int k0 = 0; k0 < K; k0 += 64) {
        s16x8 vxh0 = *(const s16x8*)(xh_p + k0);
        s16x8 vxh1 = *(const s16x8*)(xh_p + k0 + 32);
        s16x8 vxl0 = *(const s16x8*)(xl_p + k0);
        s16x8 vxl1 = *(const s16x8*)(xl_p + k0 + 32);
        s16x8 vwh  = *(const s16x8*)(wh_p + k0);
        s16x8 vwl  = *(const s16x8*)(wl_p + k0);
        __syncthreads();
        *(s16x8*)&As[0][trow][tc]      = vxh0;
        *(s16x8*)&As[0][trow][tc + 32] = vxh1;
        *(s16x8*)&As[1][trow][tc]      = vxl0;
        *(s16x8*)&As[1][trow][tc + 32] = vxl1;
        *(s16x8*)&Bs[0][trB][tcB]      = vwh;
        *(s16x8*)&Bs[1][trB][tcB]      = vwl;
        __syncthreads();

        #pragma unroll
        for (int ks = 0; ks < 2; ++ks) {
            const int ko = ks * 32 + fg;
            s16x8 ah0 = *(const s16x8*)&As[0][wr + fr][ko];
            s16x8 ah1 = *(const s16x8*)&As[0][wr + 16 + fr][ko];
            s16x8 al0 = *(const s16x8*)&As[1][wr + fr][ko];
            s16x8 al1 = *(const s16x8*)&As[1][wr + 16 + fr][ko];
            s16x8 bh  = *(const s16x8*)&Bs[0][wc + fr][ko];
            s16x8 bl  = *(const s16x8*)&Bs[1][wc + fr][ko];

            MM(acc0, ah0, bh); MM(acc0, ah0, bl); MM(acc0, al0, bh);
            MM(acc1, ah1, bh); MM(acc1, ah1, bl); MM(acc1, al1, bh);
        }
    }

    const int arow = (lane >> 4) * 4;
    const int col = n_base + wc + fr;
    const float bv = bias[col];
    #pragma unroll
    for (int mf = 0; mf < 2; ++mf) {
        const f32x4 a = mf == 0 ? acc0 : acc1;
        #pragma unroll
        for (int r = 0; r < 4; ++r) {
            const int row = m_base + wr + mf * 16 + arow + r;
            float v = fmaxf(a[r] + bv, 0.f);
            if (SPLIT_OUT) {
                unsigned short h, l;
                split2(v, h, l);
                Yh[(size_t)row * ldy + col] = h;
                Yl[(size_t)row * ldy + col] = l;
            } else {
                Yf[(size_t)row * ldy + col] = v;
            }
        }
    }
}

// ---------------------------------------------------------------------------
// Head: out[b,:] = h2[b,:] @ W3.T + b3
// ---------------------------------------------------------------------------
__global__ __launch_bounds__(256) void head_kernel(
    const float* __restrict__ h2, const float* __restrict__ W3,
    const float* __restrict__ b3, float* __restrict__ out)
{
    const int b = blockIdx.x;
    const int t = threadIdx.x;
    const float* row = h2 + (size_t)b * REP_N;

    float a0 = 0.f, a1 = 0.f, a2 = 0.f, a3 = 0.f;
    for (int k = t; k < REP_N; k += 256) {
        float x = row[k];
        a0 = fmaf(x, W3[k],             a0);
        a1 = fmaf(x, W3[REP_N + k],     a1);
        a2 = fmaf(x, W3[2 * REP_N + k], a2);
        a3 = fmaf(x, W3[3 * REP_N + k], a3);
    }
    #pragma unroll
    for (int off = 32; off > 0; off >>= 1) {
        a0 += __shfl_down(a0, off);
        a1 += __shfl_down(a1, off);
        a2 += __shfl_down(a2, off);
        a3 += __shfl_down(a3, off);
    }
    __shared__ float red[4][4];
    int wid = t >> 6, lane = t & 63;
    if (lane == 0) { red[wid][0] = a0; red[wid][1] = a1; red[wid][2] = a2; red[wid][3] = a3; }
    __syncthreads();
    if (t < 4) {
        out[b * 4 + t] = red[0][t] + red[1][t] + red[2][t] + red[3][t] + b3[t];
    }
}

extern "C" void kernel_launch(void* const* d_in, const int* in_sizes, int n_in,
                              void* d_out, int out_size, void* d_ws, size_t ws_size,
                              hipStream_t stream) {
    const float* p1 = (const float*)d_in[0];
    const float* p2 = (const float*)d_in[1];
    const float* W1 = (const float*)d_in[2];
    const float* b1 = (const float*)d_in[3];
    const float* W2 = (const float*)d_in[4];
    const float* b2 = (const float*)d_in[5];
    const float* W3 = (const float*)d_in[6];
    const float* b3 = (const float*)d_in[7];
    float* out = (float*)d_out;

    char* ws = (char*)d_ws;
    unsigned short* xh  = (unsigned short*)(ws + 0);         // 1.31 MB
    unsigned short* xl  = (unsigned short*)(ws + 1310720);   // 1.31 MB
    unsigned short* w1h = (unsigned short*)(ws + 2621440);   // 1.31 MB
    unsigned short* w1l = (unsigned short*)(ws + 3932160);   // 1.31 MB
    float*          h2  = (float*)(ws + 0);                  // 4.19 MB (reuse after GEMM1)
    unsigned short* h1h = (unsigned short*)(ws + 5242880);   // 2.10 MB
    unsigned short* h1l = (unsigned short*)(ws + 7340032);   // 2.10 MB
    unsigned short* w2h = (unsigned short*)(ws + 9437184);   // 2.10 MB
    unsigned short* w2l = (unsigned short*)(ws + 11534336);  // 2.10 MB

    // Fused corr + weight-prep (interleaved block routing, counted-vmcnt corr)
    corr_prep_kernel<<<4608, 256, 0, stream>>>(
        p1, p2, W1, W2, xh, xl, w1h, w1l, w2h, w2l);

    // GEMM1: h1 = relu(x @ W1g.T + b1), split output planes
    gemm_mfma<true><<<dim3(32, 16), 256, 0, stream>>>(
        xh, xl, KPAD, w1h, w1l, KPAD, b1, KPAD,
        (float*)nullptr, h1h, h1l, REP_N);

    // GEMM2: h2 = relu(h1 @ W2.T + b2), f32 output
    gemm_mfma<false><<<dim3(32, 16), 256, 0, stream>>>(
        h1h, h1l, REP_N, w2h, w2l, REP_N, b2, REP_N,
        h2, (unsigned short*)nullptr, (unsigned short*)nullptr, REP_N);

    head_kernel<<<BATCH, 256, 0, stream>>>(h2, W3, b3, out);
}

// Round 21
// 60.636 us; speedup vs baseline: 1.8227x; 1.0116x over previous
//
#include <hip/hip_runtime.h>

// Problem constants
#define BATCH 1024
#define RR    49        // 7*7 spatial
#define SP    12544     // 256*49 per-batch patch elems; also FLAT
#define KVALID 625      // nonzero correlation outputs per batch
#define KPAD   640      // padded K for GEMM1
#define REP_N  1024

typedef __attribute__((ext_vector_type(4))) float f32x4;
typedef __attribute__((ext_vector_type(8))) short s16x8;   // 8 bf16 (4 VGPRs)

// ---- bf16 split helpers (RNE) ----
__device__ __forceinline__ unsigned short f2bf_rne(float f) {
    unsigned int u = __float_as_uint(f);
    unsigned int r = u + 0x7FFFu + ((u >> 16) & 1u);
    return (unsigned short)(r >> 16);
}
__device__ __forceinline__ float bf2f(unsigned short h) {
    return __uint_as_float(((unsigned int)h) << 16);
}
__device__ __forceinline__ void split2(float v, unsigned short& h, unsigned short& l) {
    h = f2bf_rne(v);
    l = f2bf_rne(v - bf2f(h));
}
// Pack two floats to bf16 pair (verified numerically R4-R20).
__device__ __forceinline__ unsigned int cvtpk_bf16(float a, float b) {
    unsigned int r;
    asm("v_cvt_pk_bf16_f32 %0, %1, %2" : "=v"(r) : "v"(a), "v"(b));
    return r;
}
// Split 8 floats -> hi/lo s16x8 fragments.
__device__ __forceinline__ void cvt8(const float* v, s16x8& hv, s16x8& lv) {
    unsigned int* hp = (unsigned int*)&hv;
    unsigned int* lp = (unsigned int*)&lv;
    #pragma unroll
    for (int i = 0; i < 4; ++i) {
        float v0 = v[2 * i], v1 = v[2 * i + 1];
        unsigned int ph = cvtpk_bf16(v0, v1);
        float h0 = __uint_as_float(ph << 16);
        float h1 = __uint_as_float(ph & 0xFFFF0000u);
        unsigned int pl = cvtpk_bf16(v0 - h0, v1 - h1);
        hp[i] = ph; lp[i] = pl;
    }
}

// Decode index u in [0,25) -> (i, d), i,d in [0,7), i+d even.
__device__ __forceinline__ void dec25(int u, int& i, int& d) {
    int ii = (u >= 4) + (u >= 7) + (u >= 11) + (u >= 14) + (u >= 18) + (u >= 21);
    int cum = (7 * ii + 1) >> 1;
    i = ii;
    d = 2 * (u - cum) + (ii & 1);
}
// Encode (i,d) -> [0,25), inverse of dec25.
__device__ __forceinline__ int enc25(int i, int d) {
    return ((7 * i + 1) >> 1) + ((d - (i & 1)) >> 1);
}

// Compact index a in [0,640) -> flat column into W1's FLAT dim (a>=625 unused).
__device__ __forceinline__ int kflat_of(int a) {
    int ar = a / 25, ac = a % 25;
    int i, dy, j, dx;
    dec25(ar, i, dy);
    dec25(ac, j, dx);
    int pi = (dy + 16 - i) >> 1;
    int pj = (dx + 16 - j) >> 1;
    return (pi * 16 + pj) * 49 + i * 7 + j;
}

#define MM(d, a, b) d = __builtin_amdgcn_mfma_f32_16x16x32_bf16(a, b, d, 0, 0, 0)

// ---------------------------------------------------------------------------
// MEGA kernel: corr (parity Gram, verified R9/R12) + W1/W2 prep fused.
// Block routing (interleaved): bid<2048 even -> corr batch bid/2; odd ->
// W1-prep bid/2; bid>=2048 -> prep 1024+(bid-2048).
// corr: 8 half-chunks (32 ch) double-buffered via global_load_lds width=16,
// counted vmcnt (T4). CHANGE vs R20: LDS trimmed 35.3 -> 28 KB (dummy bq7
// load removed -> odd waves issue 3 loads with per-wave vmcnt(3); epilogue
// SX staging removed -> direct scattered global stores) => 5 blocks/CU.
// ---------------------------------------------------------------------------
__global__ __launch_bounds__(256) void corr_prep_kernel(
    const float* __restrict__ p1, const float* __restrict__ p2,
    const float* __restrict__ W1, const float* __restrict__ W2,
    unsigned short* __restrict__ xh, unsigned short* __restrict__ xl,
    unsigned short* __restrict__ w1h, unsigned short* __restrict__ w1l,
    unsigned short* __restrict__ w2h, unsigned short* __restrict__ w2l)
{
    __shared__ float4 Tb[2][2][448];       // [buf][tensor][7*64] = 28 KB

    const int bid = blockIdx.x;
    const int t   = threadIdx.x;

    bool isCorr = false;
    int cid = 0, pid = 0;
    if (bid < 2048) {
        if ((bid & 1) == 0) { isCorr = true; cid = bid >> 1; }
        else                { pid = bid >> 1; }
    } else {
        pid = 1024 + (bid - 2048);
    }

    if (!isCorr) {
        // ---- weight prep branch (block-uniform) ----
        if (pid < 2560) {
            int idx = pid * 256 + t;             // over REP_N*KPAD
            int n = idx / KPAD, a = idx - n * KPAD;
            float v = 0.f;
            if (a < KVALID) v = W1[(size_t)n * SP + kflat_of(a)];
            unsigned short h, l;
            split2(v, h, l);
            w1h[idx] = h; w1l[idx] = l;
        } else {
            int idx = ((pid - 2560) * 256 + t) * 4;   // over REP_N*REP_N
            float4 v = *(const float4*)&W2[idx];
            unsigned short h0, l0, h1, l1, h2, l2, h3, l3;
            split2(v.x, h0, l0); split2(v.y, h1, l1);
            split2(v.z, h2, l2); split2(v.w, h3, l3);
            *(ushort4*)&w2h[idx] = make_ushort4(h0, h1, h2, h3);
            *(ushort4*)&w2l[idx] = make_ushort4(l0, l1, l2, l3);
        }
        return;
    }

    // ---- corr branch ----
    const float* P1 = p1 + (size_t)cid * SP;
    const float* P2 = p2 + (size_t)cid * SP;

    const int wv   = t >> 6;
    const int lane = t & 63;
    const int fr   = lane & 15;        // class-pos index (A row / B col)
    const int fg   = (lane >> 4) * 8;  // k-offset within 32-row tile

    // parity-class geometry
    const int ci = wv >> 1, cj = wv & 1;
    const int nj = 4 - cj;
    const int clsN = (4 - ci) * nj;          // 16 / 12 / 12 / 9
    const int pr = (fr < clsN) ? fr : 0;
    const int sPos = (2 * (pr / nj) + ci) * 7 + (2 * (pr % nj) + cj);

    // staging role: waves 0,1 -> p1; waves 2,3 -> p2. Half-chunk = 32ch*49
    // = 1568 floats = 392 float4. Even staging waves (wv&1==0) issue 4
    // loads (bq 0..3, dest [0,256)); odd waves issue 3 (bq 4..6, dest
    // [256,448); bq6's src-clamped lanes land in pad [392,448)). vmcnt
    // waits are PER-WAVE, so counts differ by role (4 vs 3).
    const float* PS = (wv < 2) ? P1 : P2;
    const int tens  = wv >> 1;
    const int start = (wv & 1) * 4;          // bq range [0,4) or [4,7)
    const int nb    = (wv & 1) ? 3 : 4;      // loads per stage (wave-uniform)

    #define STAGE(buf, hc)                                                     \
        do {                                                                   \
            const int off_ = (hc) * 1568;                                      \
            float4* T_ = &Tb[(buf)][tens][0];                                  \
            _Pragma("unroll")                                                  \
            for (int j_ = 0; j_ < 4; ++j_) {                                   \
                if (j_ < nb) {                                                 \
                    const int bq_  = start + j_;                               \
                    const int src_ = min(bq_ * 64 + lane, 391);                \
                    __builtin_amdgcn_global_load_lds(                          \
                        (const __attribute__((address_space(1))) unsigned int*)\
                            (PS + off_ + src_ * 4),                            \
                        (__attribute__((address_space(3))) unsigned int*)      \
                            (T_ + bq_ * 64),                                   \
                        16, 0, 0);                                             \
                }                                                              \
            }                                                                  \
        } while (0)

    STAGE(0, 0);   // prologue: 2 stages in flight (8 or 6 loads per wave)
    STAGE(1, 1);

    f32x4 acc = {};
    #pragma unroll
    for (int hc = 0; hc < 8; ++hc) {
        // Wait ONLY for the current stage's loads (oldest in the queue);
        // the next stage's loads remain outstanding across the barrier.
        if (hc < 7) {
            if (wv & 1) asm volatile("s_waitcnt vmcnt(3)" ::: "memory");
            else        asm volatile("s_waitcnt vmcnt(4)" ::: "memory");
        } else {
            asm volatile("s_waitcnt vmcnt(0)" ::: "memory");
        }
        __builtin_amdgcn_s_barrier();          // all waves' current loads landed
        __builtin_amdgcn_sched_barrier(0);     // pin: no ds_read hoisted above

        const int cur = hc & 1;
        const float* Tf1 = (const float*)&Tb[cur][0][0];
        const float* Tf2 = (const float*)&Tb[cur][1][0];
        const int kb = fg * RR + sPos;
        float av[8], bv[8];
        #pragma unroll
        for (int i = 0; i < 8; ++i) {
            av[i] = Tf1[kb + i * RR];
            bv[i] = Tf2[kb + i * RR];
        }
        s16x8 ah, al, bh, bl;
        cvt8(av, ah, al);
        cvt8(bv, bh, bl);
        MM(acc, ah, bh);
        MM(acc, ah, bl);
        MM(acc, al, bh);

        __builtin_amdgcn_sched_barrier(0);
        __builtin_amdgcn_s_barrier();          // all waves done reading buf[cur]
        if (hc < 6) STAGE(cur, hc + 2);        // refill the buffer just freed
    }
    #undef STAGE

    // Epilogue (verified R9 mapping): direct scattered global stores.
    // C/D layout: col = lane&15, row = 4*(lane>>4)+r.
    unsigned short* rh = xh + (size_t)cid * KPAD;
    unsigned short* rl = xl + (size_t)cid * KPAD;
    if (t < KPAD - KVALID) {                   // zero the 15-element pad tail
        rh[KVALID + t] = 0;
        rl[KVALID + t] = 0;
    }
    const int arow = (lane >> 4) * 4;
    if (fr < clsN) {
        const int dy = 2 * (fr / nj) + ci;
        const int dx = 2 * (fr % nj) + cj;
        #pragma unroll
        for (int r = 0; r < 4; ++r) {
            const int rowp = arow + r;
            if (rowp < clsN) {
                const int i1 = 2 * (rowp / nj) + ci;
                const int j1 = 2 * (rowp % nj) + cj;
                const int aidx = enc25(i1, dy) * 25 + enc25(j1, dx);
                unsigned short hh, ll;
                split2(acc[r], hh, ll);
                rh[aidx] = hh; rl[aidx] = ll;
            }
        }
    }
}

// ---------------------------------------------------------------------------
// MFMA GEMM: Y[m,n] = relu( sum_k X[m,k]*W[n,k] + bias[n] )
// X,W as bf16 hi/lo planes; products hh + hl + lh. 64x32 tile, BK=64,
// grid (N/32, M/64) = 512 blocks -> 2 blocks/CU. 4 waves, each 32x16.
// (unchanged from R14/R17/R20 best)
// ---------------------------------------------------------------------------
template<bool SPLIT_OUT>
__global__ __launch_bounds__(256) void gemm_mfma(
    const unsigned short* __restrict__ Xh, const unsigned short* __restrict__ Xl, int ldx,
    const unsigned short* __restrict__ Wh, const unsigned short* __restrict__ Wl, int ldw,
    const float* __restrict__ bias, int K,
    float* __restrict__ Yf, unsigned short* __restrict__ Yh, unsigned short* __restrict__ Yl,
    int ldy)
{
    __shared__ unsigned short As[2][64][72];   // 18.4 KB
    __shared__ unsigned short Bs[2][32][72];   // 9.2 KB

    const int t = threadIdx.x;
    const int m_base = blockIdx.y * 64;
    const int n_base = blockIdx.x * 32;

    const int trow = t >> 2;          // 0..63  (A rows)
    const int tc   = (t & 3) * 8;     // 0,8,16,24
    const int trB  = t >> 3;          // 0..31  (B rows)
    const int tcB  = (t & 7) * 8;     // 0..56

    const unsigned short* xh_p = Xh + (size_t)(m_base + trow) * ldx + tc;
    const unsigned short* xl_p = Xl + (size_t)(m_base + trow) * ldx + tc;
    const unsigned short* wh_p = Wh + (size_t)(n_base + trB) * ldw + tcB;
    const unsigned short* wl_p = Wl + (size_t)(n_base + trB) * ldw + tcB;

    const int wv   = t >> 6;
    const int lane = t & 63;
    const int wr = (wv >> 1) * 32;    // 0 or 32
    const int wc = (wv & 1) * 16;     // 0 or 16
    const int fr = lane & 15;
    const int fg = (lane >> 4) * 8;

    f32x4 acc0 = {}, acc1 = {};

    for (int k0 = 0; k0 < K; k0 += 64) {
        s16x8 vxh0 = *(const s16x8*)(xh_p + k0);
        s16x8 vxh1 = *(const s16x8*)(xh_p + k0 + 32);
        s16x8 vxl0 = *(const s16x8*)(xl_p + k0);
        s16x8 vxl1 = *(const s16x8*)(xl_p + k0 + 32);
        s16x8 vwh  = *(const s16x8*)(wh_p + k0);
        s16x8 vwl  = *(const s16x8*)(wl_p + k0);
        __syncthreads();
        *(s16x8*)&As[0][trow][tc]      = vxh0;
        *(s16x8*)&As[0][trow][tc + 32] = vxh1;
        *(s16x8*)&As[1][trow][tc]      = vxl0;
        *(s16x8*)&As[1][trow][tc + 32] = vxl1;
        *(s16x8*)&Bs[0][trB][tcB]      = vwh;
        *(s16x8*)&Bs[1][trB][tcB]      = vwl;
        __syncthreads();

        #pragma unroll
        for (int ks = 0; ks < 2; ++ks) {
            const int ko = ks * 32 + fg;
            s16x8 ah0 = *(const s16x8*)&As[0][wr + fr][ko];
            s16x8 ah1 = *(const s16x8*)&As[0][wr + 16 + fr][ko];
            s16x8 al0 = *(const s16x8*)&As[1][wr + fr][ko];
            s16x8 al1 = *(const s16x8*)&As[1][wr + 16 + fr][ko];
            s16x8 bh  = *(const s16x8*)&Bs[0][wc + fr][ko];
            s16x8 bl  = *(const s16x8*)&Bs[1][wc + fr][ko];

            MM(acc0, ah0, bh); MM(acc0, ah0, bl); MM(acc0, al0, bh);
            MM(acc1, ah1, bh); MM(acc1, ah1, bl); MM(acc1, al1, bh);
        }
    }

    const int arow = (lane >> 4) * 4;
    const int col = n_base + wc + fr;
    const float bv = bias[col];
    #pragma unroll
    for (int mf = 0; mf < 2; ++mf) {
        const f32x4 a = mf == 0 ? acc0 : acc1;
        #pragma unroll
        for (int r = 0; r < 4; ++r) {
            const int row = m_base + wr + mf * 16 + arow + r;
            float v = fmaxf(a[r] + bv, 0.f);
            if (SPLIT_OUT) {
                unsigned short h, l;
                split2(v, h, l);
                Yh[(size_t)row * ldy + col] = h;
                Yl[(size_t)row * ldy + col] = l;
            } else {
                Yf[(size_t)row * ldy + col] = v;
            }
        }
    }
}

// ---------------------------------------------------------------------------
// Head: out[b,:] = h2[b,:] @ W3.T + b3
// ---------------------------------------------------------------------------
__global__ __launch_bounds__(256) void head_kernel(
    const float* __restrict__ h2, const float* __restrict__ W3,
    const float* __restrict__ b3, float* __restrict__ out)
{
    const int b = blockIdx.x;
    const int t = threadIdx.x;
    const float* row = h2 + (size_t)b * REP_N;

    float a0 = 0.f, a1 = 0.f, a2 = 0.f, a3 = 0.f;
    for (int k = t; k < REP_N; k += 256) {
        float x = row[k];
        a0 = fmaf(x, W3[k],             a0);
        a1 = fmaf(x, W3[REP_N + k],     a1);
        a2 = fmaf(x, W3[2 * REP_N + k], a2);
        a3 = fmaf(x, W3[3 * REP_N + k], a3);
    }
    #pragma unroll
    for (int off = 32; off > 0; off >>= 1) {
        a0 += __shfl_down(a0, off);
        a1 += __shfl_down(a1, off);
        a2 += __shfl_down(a2, off);
        a3 += __shfl_down(a3, off);
    }
    __shared__ float red[4][4];
    int wid = t >> 6, lane = t & 63;
    if (lane == 0) { red[wid][0] = a0; red[wid][1] = a1; red[wid][2] = a2; red[wid][3] = a3; }
    __syncthreads();
    if (t < 4) {
        out[b * 4 + t] = red[0][t] + red[1][t] + red[2][t] + red[3][t] + b3[t];
    }
}

extern "C" void kernel_launch(void* const* d_in, const int* in_sizes, int n_in,
                              void* d_out, int out_size, void* d_ws, size_t ws_size,
                              hipStream_t stream) {
    const float* p1 = (const float*)d_in[0];
    const float* p2 = (const float*)d_in[1];
    const float* W1 = (const float*)d_in[2];
    const float* b1 = (const float*)d_in[3];
    const float* W2 = (const float*)d_in[4];
    const float* b2 = (const float*)d_in[5];
    const float* W3 = (const float*)d_in[6];
    const float* b3 = (const float*)d_in[7];
    float* out = (float*)d_out;

    char* ws = (char*)d_ws;
    unsigned short* xh  = (unsigned short*)(ws + 0);         // 1.31 MB
    unsigned short* xl  = (unsigned short*)(ws + 1310720);   // 1.31 MB
    unsigned short* w1h = (unsigned short*)(ws + 2621440);   // 1.31 MB
    unsigned short* w1l = (unsigned short*)(ws + 3932160);   // 1.31 MB
    float*          h2  = (float*)(ws + 0);                  // 4.19 MB (reuse after GEMM1)
    unsigned short* h1h = (unsigned short*)(ws + 5242880);   // 2.10 MB
    unsigned short* h1l = (unsigned short*)(ws + 7340032);   // 2.10 MB
    unsigned short* w2h = (unsigned short*)(ws + 9437184);   // 2.10 MB
    unsigned short* w2l = (unsigned short*)(ws + 11534336);  // 2.10 MB

    // Fused corr + weight-prep (interleaved routing, 28 KB LDS -> 5 blk/CU)
    corr_prep_kernel<<<4608, 256, 0, stream>>>(
        p1, p2, W1, W2, xh, xl, w1h, w1l, w2h, w2l);

    // GEMM1: h1 = relu(x @ W1g.T + b1), split output planes
    gemm_mfma<true><<<dim3(32, 16), 256, 0, stream>>>(
        xh, xl, KPAD, w1h, w1l, KPAD, b1, KPAD,
        (float*)nullptr, h1h, h1l, REP_N);

    // GEMM2: h2 = relu(h1 @ W2.T + b2), f32 output
    gemm_mfma<false><<<dim3(32, 16), 256, 0, stream>>>(
        h1h, h1l, REP_N, w2h, w2l, REP_N, b2, REP_N,
        h2, (unsigned short*)nullptr, (unsigned short*)nullptr, REP_N);

    head_kernel<<<BATCH, 256, 0, stream>>>(h2, W3, b3, out);
}

// Round 22
// 60.207 us; speedup vs baseline: 1.8357x; 1.0071x over previous
//
#include <hip/hip_runtime.h>

// Problem constants
#define BATCH 1024
#define RR    49        // 7*7 spatial
#define SP    12544     // 256*49 per-batch patch elems; also FLAT
#define KVALID 625      // nonzero correlation outputs per batch
#define KPAD   640      // padded K for GEMM1
#define REP_N  1024

typedef __attribute__((ext_vector_type(4))) float f32x4;
typedef __attribute__((ext_vector_type(8))) short s16x8;   // 8 bf16 (4 VGPRs)

// ---- bf16 split helpers (RNE) ----
__device__ __forceinline__ unsigned short f2bf_rne(float f) {
    unsigned int u = __float_as_uint(f);
    unsigned int r = u + 0x7FFFu + ((u >> 16) & 1u);
    return (unsigned short)(r >> 16);
}
__device__ __forceinline__ float bf2f(unsigned short h) {
    return __uint_as_float(((unsigned int)h) << 16);
}
__device__ __forceinline__ void split2(float v, unsigned short& h, unsigned short& l) {
    h = f2bf_rne(v);
    l = f2bf_rne(v - bf2f(h));
}
// Pack two floats to bf16 pair (verified numerically R4-R21).
__device__ __forceinline__ unsigned int cvtpk_bf16(float a, float b) {
    unsigned int r;
    asm("v_cvt_pk_bf16_f32 %0, %1, %2" : "=v"(r) : "v"(a), "v"(b));
    return r;
}
// Split 8 floats -> hi/lo s16x8 fragments.
__device__ __forceinline__ void cvt8(const float* v, s16x8& hv, s16x8& lv) {
    unsigned int* hp = (unsigned int*)&hv;
    unsigned int* lp = (unsigned int*)&lv;
    #pragma unroll
    for (int i = 0; i < 4; ++i) {
        float v0 = v[2 * i], v1 = v[2 * i + 1];
        unsigned int ph = cvtpk_bf16(v0, v1);
        float h0 = __uint_as_float(ph << 16);
        float h1 = __uint_as_float(ph & 0xFFFF0000u);
        unsigned int pl = cvtpk_bf16(v0 - h0, v1 - h1);
        hp[i] = ph; lp[i] = pl;
    }
}

// Decode index u in [0,25) -> (i, d), i,d in [0,7), i+d even.
__device__ __forceinline__ void dec25(int u, int& i, int& d) {
    int ii = (u >= 4) + (u >= 7) + (u >= 11) + (u >= 14) + (u >= 18) + (u >= 21);
    int cum = (7 * ii + 1) >> 1;
    i = ii;
    d = 2 * (u - cum) + (ii & 1);
}
// Encode (i,d) -> [0,25), inverse of dec25.
__device__ __forceinline__ int enc25(int i, int d) {
    return ((7 * i + 1) >> 1) + ((d - (i & 1)) >> 1);
}

// Compact index a in [0,640) -> flat column into W1's FLAT dim (a>=625 unused).
__device__ __forceinline__ int kflat_of(int a) {
    int ar = a / 25, ac = a % 25;
    int i, dy, j, dx;
    dec25(ar, i, dy);
    dec25(ac, j, dx);
    int pi = (dy + 16 - i) >> 1;
    int pj = (dx + 16 - j) >> 1;
    return (pi * 16 + pj) * 49 + i * 7 + j;
}

#define MM(d, a, b) d = __builtin_amdgcn_mfma_f32_16x16x32_bf16(a, b, d, 0, 0, 0)

// ---------------------------------------------------------------------------
// MEGA kernel: corr (parity Gram, verified R9/R12) + W1/W2 prep fused.
// Block routing (interleaved): bid<2048 even -> corr batch bid/2; odd ->
// W1-prep bid/2; bid>=2048 -> prep 1024+(bid-2048).
// corr: 8 half-chunks (32 ch) double-buffered via global_load_lds width=16,
// counted vmcnt (T4). 28 KB LDS -> 5 blocks/CU (R21 best).
// ---------------------------------------------------------------------------
__global__ __launch_bounds__(256) void corr_prep_kernel(
    const float* __restrict__ p1, const float* __restrict__ p2,
    const float* __restrict__ W1, const float* __restrict__ W2,
    unsigned short* __restrict__ xh, unsigned short* __restrict__ xl,
    unsigned short* __restrict__ w1h, unsigned short* __restrict__ w1l,
    unsigned short* __restrict__ w2h, unsigned short* __restrict__ w2l)
{
    __shared__ float4 Tb[2][2][448];       // [buf][tensor][7*64] = 28 KB

    const int bid = blockIdx.x;
    const int t   = threadIdx.x;

    bool isCorr = false;
    int cid = 0, pid = 0;
    if (bid < 2048) {
        if ((bid & 1) == 0) { isCorr = true; cid = bid >> 1; }
        else                { pid = bid >> 1; }
    } else {
        pid = 1024 + (bid - 2048);
    }

    if (!isCorr) {
        // ---- weight prep branch (block-uniform) ----
        if (pid < 2560) {
            int idx = pid * 256 + t;             // over REP_N*KPAD
            int n = idx / KPAD, a = idx - n * KPAD;
            float v = 0.f;
            if (a < KVALID) v = W1[(size_t)n * SP + kflat_of(a)];
            unsigned short h, l;
            split2(v, h, l);
            w1h[idx] = h; w1l[idx] = l;
        } else {
            int idx = ((pid - 2560) * 256 + t) * 4;   // over REP_N*REP_N
            float4 v = *(const float4*)&W2[idx];
            unsigned short h0, l0, h1, l1, h2, l2, h3, l3;
            split2(v.x, h0, l0); split2(v.y, h1, l1);
            split2(v.z, h2, l2); split2(v.w, h3, l3);
            *(ushort4*)&w2h[idx] = make_ushort4(h0, h1, h2, h3);
            *(ushort4*)&w2l[idx] = make_ushort4(l0, l1, l2, l3);
        }
        return;
    }

    // ---- corr branch ----
    const float* P1 = p1 + (size_t)cid * SP;
    const float* P2 = p2 + (size_t)cid * SP;

    const int wv   = t >> 6;
    const int lane = t & 63;
    const int fr   = lane & 15;        // class-pos index (A row / B col)
    const int fg   = (lane >> 4) * 8;  // k-offset within 32-row tile

    // parity-class geometry
    const int ci = wv >> 1, cj = wv & 1;
    const int nj = 4 - cj;
    const int clsN = (4 - ci) * nj;          // 16 / 12 / 12 / 9
    const int pr = (fr < clsN) ? fr : 0;
    const int sPos = (2 * (pr / nj) + ci) * 7 + (2 * (pr % nj) + cj);

    // staging role: waves 0,1 -> p1; waves 2,3 -> p2. Half-chunk = 32ch*49
    // = 1568 floats = 392 float4. Even staging waves issue 4 loads (bq 0..3,
    // dest [0,256)); odd waves issue 3 (bq 4..6, dest [256,448); bq6's
    // src-clamped lanes land in pad [392,448)). vmcnt waits are PER-WAVE.
    const float* PS = (wv < 2) ? P1 : P2;
    const int tens  = wv >> 1;
    const int start = (wv & 1) * 4;          // bq range [0,4) or [4,7)
    const int nb    = (wv & 1) ? 3 : 4;      // loads per stage (wave-uniform)

    #define STAGE(buf, hc)                                                     \
        do {                                                                   \
            const int off_ = (hc) * 1568;                                      \
            float4* T_ = &Tb[(buf)][tens][0];                                  \
            _Pragma("unroll")                                                  \
            for (int j_ = 0; j_ < 4; ++j_) {                                   \
                if (j_ < nb) {                                                 \
                    const int bq_  = start + j_;                               \
                    const int src_ = min(bq_ * 64 + lane, 391);                \
                    __builtin_amdgcn_global_load_lds(                          \
                        (const __attribute__((address_space(1))) unsigned int*)\
                            (PS + off_ + src_ * 4),                            \
                        (__attribute__((address_space(3))) unsigned int*)      \
                            (T_ + bq_ * 64),                                   \
                        16, 0, 0);                                             \
                }                                                              \
            }                                                                  \
        } while (0)

    STAGE(0, 0);   // prologue: 2 stages in flight (8 or 6 loads per wave)
    STAGE(1, 1);

    f32x4 acc = {};
    #pragma unroll
    for (int hc = 0; hc < 8; ++hc) {
        // Wait ONLY for the current stage's loads (oldest in the queue);
        // the next stage's loads remain outstanding across the barrier.
        if (hc < 7) {
            if (wv & 1) asm volatile("s_waitcnt vmcnt(3)" ::: "memory");
            else        asm volatile("s_waitcnt vmcnt(4)" ::: "memory");
        } else {
            asm volatile("s_waitcnt vmcnt(0)" ::: "memory");
        }
        __builtin_amdgcn_s_barrier();          // all waves' current loads landed
        __builtin_amdgcn_sched_barrier(0);     // pin: no ds_read hoisted above

        const int cur = hc & 1;
        const float* Tf1 = (const float*)&Tb[cur][0][0];
        const float* Tf2 = (const float*)&Tb[cur][1][0];
        const int kb = fg * RR + sPos;
        float av[8], bv[8];
        #pragma unroll
        for (int i = 0; i < 8; ++i) {
            av[i] = Tf1[kb + i * RR];
            bv[i] = Tf2[kb + i * RR];
        }
        s16x8 ah, al, bh, bl;
        cvt8(av, ah, al);
        cvt8(bv, bh, bl);
        MM(acc, ah, bh);
        MM(acc, ah, bl);
        MM(acc, al, bh);

        __builtin_amdgcn_sched_barrier(0);
        __builtin_amdgcn_s_barrier();          // all waves done reading buf[cur]
        if (hc < 6) STAGE(cur, hc + 2);        // refill the buffer just freed
    }
    #undef STAGE

    // Epilogue (verified R9 mapping): direct scattered global stores.
    // C/D layout: col = lane&15, row = 4*(lane>>4)+r.
    unsigned short* rh = xh + (size_t)cid * KPAD;
    unsigned short* rl = xl + (size_t)cid * KPAD;
    if (t < KPAD - KVALID) {                   // zero the 15-element pad tail
        rh[KVALID + t] = 0;
        rl[KVALID + t] = 0;
    }
    const int arow = (lane >> 4) * 4;
    if (fr < clsN) {
        const int dy = 2 * (fr / nj) + ci;
        const int dx = 2 * (fr % nj) + cj;
        #pragma unroll
        for (int r = 0; r < 4; ++r) {
            const int rowp = arow + r;
            if (rowp < clsN) {
                const int i1 = 2 * (rowp / nj) + ci;
                const int j1 = 2 * (rowp % nj) + cj;
                const int aidx = enc25(i1, dy) * 25 + enc25(j1, dx);
                unsigned short hh, ll;
                split2(acc[r], hh, ll);
                rh[aidx] = hh; rl[aidx] = ll;
            }
        }
    }
}

// ---------------------------------------------------------------------------
// MFMA GEMM: Y[m,n] = relu( sum_k X[m,k]*W[n,k] + bias[n] )
// X,W as bf16 hi/lo planes; products hh + hl + lh. 64x32 tile, BK=64,
// grid (N/32, M/64) = 512 blocks -> 2 blocks/CU. 4 waves, each 32x16.
// ---------------------------------------------------------------------------
template<bool SPLIT_OUT>
__global__ __launch_bounds__(256) void gemm_mfma(
    const unsigned short* __restrict__ Xh, const unsigned short* __restrict__ Xl, int ldx,
    const unsigned short* __restrict__ Wh, const unsigned short* __restrict__ Wl, int ldw,
    const float* __restrict__ bias, int K,
    float* __restrict__ Yf, unsigned short* __restrict__ Yh, unsigned short* __restrict__ Yl,
    int ldy)
{
    __shared__ unsigned short As[2][64][72];   // 18.4 KB
    __shared__ unsigned short Bs[2][32][72];   // 9.2 KB

    const int t = threadIdx.x;
    const int m_base = blockIdx.y * 64;
    const int n_base = blockIdx.x * 32;

    const int trow = t >> 2;          // 0..63  (A rows)
    const int tc   = (t & 3) * 8;     // 0,8,16,24
    const int trB  = t >> 3;          // 0..31  (B rows)
    const int tcB  = (t & 7) * 8;     // 0..56

    const unsigned short* xh_p = Xh + (size_t)(m_base + trow) * ldx + tc;
    const unsigned short* xl_p = Xl + (size_t)(m_base + trow) * ldx + tc;
    const unsigned short* wh_p = Wh + (size_t)(n_base + trB) * ldw + tcB;
    const unsigned short* wl_p = Wl + (size_t)(n_base + trB) * ldw + tcB;

    const int wv   = t >> 6;
    const int lane = t & 63;
    const int wr = (wv >> 1) * 32;    // 0 or 32
    const int wc = (wv & 1) * 16;     // 0 or 16
    const int fr = lane & 15;
    const int fg = (lane >> 4) * 8;

    f32x4 acc0 = {}, acc1 = {};

    for (int k0 = 0; k0 < K; k0 += 64) {
        s16x8 vxh0 = *(const s16x8*)(xh_p + k0);
        s16x8 vxh1 = *(const s16x8*)(xh_p + k0 + 32);
        s16x8 vxl0 = *(const s16x8*)(xl_p + k0);
        s16x8 vxl1 = *(const s16x8*)(xl_p + k0 + 32);
        s16x8 vwh  = *(const s16x8*)(wh_p + k0);
        s16x8 vwl  = *(const s16x8*)(wl_p + k0);
        __syncthreads();
        *(s16x8*)&As[0][trow][tc]      = vxh0;
        *(s16x8*)&As[0][trow][tc + 32] = vxh1;
        *(s16x8*)&As[1][trow][tc]      = vxl0;
        *(s16x8*)&As[1][trow][tc + 32] = vxl1;
        *(s16x8*)&Bs[0][trB][tcB]      = vwh;
        *(s16x8*)&Bs[1][trB][tcB]      = vwl;
        __syncthreads();

        #pragma unroll
        for (int ks = 0; ks < 2; ++ks) {
            const int ko = ks * 32 + fg;
            s16x8 ah0 = *(const s16x8*)&As[0][wr + fr][ko];
            s16x8 ah1 = *(const s16x8*)&As[0][wr + 16 + fr][ko];
            s16x8 al0 = *(const s16x8*)&As[1][wr + fr][ko];
            s16x8 al1 = *(const s16x8*)&As[1][wr + 16 + fr][ko];
            s16x8 bh  = *(const s16x8*)&Bs[0][wc + fr][ko];
            s16x8 bl  = *(const s16x8*)&Bs[1][wc + fr][ko];

            MM(acc0, ah0, bh); MM(acc0, ah0, bl); MM(acc0, al0, bh);
            MM(acc1, ah1, bh); MM(acc1, ah1, bl); MM(acc1, al1, bh);
        }
    }

    const int arow = (lane >> 4) * 4;
    const int col = n_base + wc + fr;
    const float bv = bias[col];
    #pragma unroll
    for (int mf = 0; mf < 2; ++mf) {
        const f32x4 a = mf == 0 ? acc0 : acc1;
        #pragma unroll
        for (int r = 0; r < 4; ++r) {
            const int row = m_base + wr + mf * 16 + arow + r;
            float v = fmaxf(a[r] + bv, 0.f);
            if (SPLIT_OUT) {
                unsigned short h, l;
                split2(v, h, l);
                Yh[(size_t)row * ldy + col] = h;
                Yl[(size_t)row * ldy + col] = l;
            } else {
                Yf[(size_t)row * ldy + col] = v;
            }
        }
    }
}

// ---------------------------------------------------------------------------
// Head: out[b,:] = h2[b,:] @ W3.T + b3
// ---------------------------------------------------------------------------
__global__ __launch_bounds__(256) void head_kernel(
    const float* __restrict__ h2, const float* __restrict__ W3,
    const float* __restrict__ b3, float* __restrict__ out)
{
    const int b = blockIdx.x;
    const int t = threadIdx.x;
    const float* row = h2 + (size_t)b * REP_N;

    float a0 = 0.f, a1 = 0.f, a2 = 0.f, a3 = 0.f;
    for (int k = t; k < REP_N; k += 256) {
        float x = row[k];
        a0 = fmaf(x, W3[k],             a0);
        a1 = fmaf(x, W3[REP_N + k],     a1);
        a2 = fmaf(x, W3[2 * REP_N + k], a2);
        a3 = fmaf(x, W3[3 * REP_N + k], a3);
    }
    #pragma unroll
    for (int off = 32; off > 0; off >>= 1) {
        a0 += __shfl_down(a0, off);
        a1 += __shfl_down(a1, off);
        a2 += __shfl_down(a2, off);
        a3 += __shfl_down(a3, off);
    }
    __shared__ float red[4][4];
    int wid = t >> 6, lane = t & 63;
    if (lane == 0) { red[wid][0] = a0; red[wid][1] = a1; red[wid][2] = a2; red[wid][3] = a3; }
    __syncthreads();
    if (t < 4) {
        out[b * 4 + t] = red[0][t] + red[1][t] + red[2][t] + red[3][t] + b3[t];
    }
}

extern "C" void kernel_launch(void* const* d_in, const int* in_sizes, int n_in,
                              void* d_out, int out_size, void* d_ws, size_t ws_size,
                              hipStream_t stream) {
    const float* p1 = (const float*)d_in[0];
    const float* p2 = (const float*)d_in[1];
    const float* W1 = (const float*)d_in[2];
    const float* b1 = (const float*)d_in[3];
    const float* W2 = (const float*)d_in[4];
    const float* b2 = (const float*)d_in[5];
    const float* W3 = (const float*)d_in[6];
    const float* b3 = (const float*)d_in[7];
    float* out = (float*)d_out;

    char* ws = (char*)d_ws;
    unsigned short* xh  = (unsigned short*)(ws + 0);         // 1.31 MB
    unsigned short* xl  = (unsigned short*)(ws + 1310720);   // 1.31 MB
    unsigned short* w1h = (unsigned short*)(ws + 2621440);   // 1.31 MB
    unsigned short* w1l = (unsigned short*)(ws + 3932160);   // 1.31 MB
    float*          h2  = (float*)(ws + 0);                  // 4.19 MB (reuse after GEMM1)
    unsigned short* h1h = (unsigned short*)(ws + 5242880);   // 2.10 MB
    unsigned short* h1l = (unsigned short*)(ws + 7340032);   // 2.10 MB
    unsigned short* w2h = (unsigned short*)(ws + 9437184);   // 2.10 MB
    unsigned short* w2l = (unsigned short*)(ws + 11534336);  // 2.10 MB

    // Fused corr + weight-prep (interleaved routing, 28 KB LDS -> 5 blk/CU)
    corr_prep_kernel<<<4608, 256, 0, stream>>>(
        p1, p2, W1, W2, xh, xl, w1h, w1l, w2h, w2l);

    // GEMM1: h1 = relu(x @ W1g.T + b1), split output planes
    gemm_mfma<true><<<dim3(32, 16), 256, 0, stream>>>(
        xh, xl, KPAD, w1h, w1l, KPAD, b1, KPAD,
        (float*)nullptr, h1h, h1l, REP_N);

    // GEMM2: h2 = relu(h1 @ W2.T + b2), f32 output
    gemm_mfma<false><<<dim3(32, 16), 256, 0, stream>>>(
        h1h, h1l, REP_N, w2h, w2l, REP_N, b2, REP_N,
        h2, (unsigned short*)nullptr, (unsigned short*)nullptr, REP_N);

    head_kernel<<<BATCH, 256, 0, stream>>>(h2, W3, b3, out);
}